// Round 1
// baseline (357.271 us; speedup 1.0000x reference)
//
#include <hip/hip_runtime.h>

#define N_NODES 50000
#define N_EDGES 600000
#define DIM     128
#define VOCAB   512
#define LN_EPS  1e-5f

// ---------------------------------------------------------------------------
// K0: init degree (self-loop weight 1.0) and per-dst edge counts
__global__ void init_kernel(float* degf, int* cnt, int n) {
    int i = blockIdx.x * blockDim.x + threadIdx.x;
    if (i < n) { degf[i] = 1.0f; cnt[i] = 0; }
}

// K1: accumulate weighted in-degree and edge counts per destination
__global__ void deg_count_kernel(const int* __restrict__ ei, const float* __restrict__ ew,
                                 float* degf, int* cnt, int E) {
    int e = blockIdx.x * blockDim.x + threadIdx.x;
    if (e < E) {
        int c = ei[E + e];                 // edge_index[1][e] = destination
        atomicAdd(&degf[c], ew[e]);
        atomicAdd(&cnt[c], 1);
    }
}

// K2a: per-block exclusive scan of cnt (chunk of 1024) + dis = rsqrt(deg)
__global__ void scan_a(const int* __restrict__ cnt, const float* __restrict__ degf,
                       float* dis, int* row_ptr, int* bsum, int n) {
    __shared__ int sd[1024];
    int t = threadIdx.x;
    int i = blockIdx.x * 1024 + t;
    int v = (i < n) ? cnt[i] : 0;
    if (i < n) dis[i] = rsqrtf(degf[i]);   // deg >= 1 always (self loop)
    sd[t] = v;
    __syncthreads();
    for (int off = 1; off < 1024; off <<= 1) {
        int add = (t >= off) ? sd[t - off] : 0;
        __syncthreads();
        sd[t] += add;
        __syncthreads();
    }
    if (i < n) row_ptr[i] = sd[t] - v;     // block-local exclusive
    if (t == 1023) bsum[blockIdx.x] = sd[t];
}

// K2b: scan the (<=64) block sums
__global__ void scan_b(const int* __restrict__ bsum, int* bofs, int nb) {
    int t = threadIdx.x;                   // 64 threads, 1 wave
    int v = (t < nb) ? bsum[t] : 0;
    int incl = v;
    #pragma unroll
    for (int off = 1; off < 64; off <<= 1) {
        int up = __shfl_up(incl, off, 64);
        if (t >= off) incl += up;
    }
    if (t < nb) bofs[t] = incl - v;
}

// K2c: add block offsets -> final row_ptr; copy to fill cursor
__global__ void scan_c(int* row_ptr, int* fill, const int* __restrict__ bofs, int n, int E) {
    int i = blockIdx.x * 1024 + threadIdx.x;
    if (i < n) {
        int rp = row_ptr[i] + bofs[blockIdx.x];
        row_ptr[i] = rp;
        fill[i] = rp;
    }
    if (i == 0) row_ptr[n] = E;
}

// K3: scatter edges into CSR buckets; precompute norm = dis[src]*ew*dis[dst]
__global__ void scatter_kernel(const int* __restrict__ ei, const float* __restrict__ ew,
                               const float* __restrict__ dis, int* fill,
                               int* csr_src, float* csr_w, int E) {
    int e = blockIdx.x * blockDim.x + threadIdx.x;
    if (e < E) {
        int s = ei[e];                     // source
        int c = ei[E + e];                 // destination
        int pos = atomicAdd(&fill[c], 1);
        csr_src[pos] = s;
        csr_w[pos] = dis[s] * ew[e] * dis[c];
    }
}

// ---------------------------------------------------------------------------
// Tiled fp32 matmul: H[M x 128] = X[M x 128] @ W[128 x 128]
// block = 256 threads, 64-row output tile, K staged in chunks of 32.
// thread (tx = tid&31, ty = tid>>5) owns 8 rows x 4 cols.
__global__ __launch_bounds__(256) void matmul128(const float* __restrict__ X,
                                                 const float* __restrict__ W,
                                                 float* __restrict__ H, int M) {
    __shared__ float Wt[32 * 128];         // 16 KB
    __shared__ float Xt[64 * 36];          // 9 KB (pad 32 -> 36 floats/row)
    int tid = threadIdx.x;
    int tx = tid & 31, ty = tid >> 5;
    int r0 = blockIdx.x * 64;
    float acc[8][4];
    #pragma unroll
    for (int j = 0; j < 8; j++)
        #pragma unroll
        for (int c = 0; c < 4; c++) acc[j][c] = 0.f;

    for (int kb = 0; kb < 128; kb += 32) {
        __syncthreads();
        // stage W chunk (rows kb..kb+31, contiguous 4096 floats)
        #pragma unroll
        for (int q = 0; q < 4; q++) {
            int f = q * 256 + tid;         // float4 index 0..1023
            ((float4*)Wt)[f] = *(const float4*)(W + kb * 128 + f * 4);
        }
        // stage X chunk (64 rows x 32 cols)
        #pragma unroll
        for (int q = 0; q < 2; q++) {
            int f = q * 256 + tid;         // 0..511
            int row = f >> 3, cs = f & 7;
            int gr = r0 + row;
            float4 xv = make_float4(0.f, 0.f, 0.f, 0.f);
            if (gr < M) xv = *(const float4*)(X + (size_t)gr * 128 + kb + cs * 4);
            *(float4*)(Xt + row * 36 + cs * 4) = xv;
        }
        __syncthreads();
        #pragma unroll
        for (int k = 0; k < 32; k += 4) {
            float wv[4][4];
            #pragma unroll
            for (int kk = 0; kk < 4; kk++) {
                float4 t4 = *(const float4*)(Wt + (k + kk) * 128 + tx * 4);
                wv[kk][0] = t4.x; wv[kk][1] = t4.y; wv[kk][2] = t4.z; wv[kk][3] = t4.w;
            }
            #pragma unroll
            for (int j = 0; j < 8; j++) {
                float4 xv = *(const float4*)(Xt + (ty * 8 + j) * 36 + k);
                float xs[4] = {xv.x, xv.y, xv.z, xv.w};
                #pragma unroll
                for (int kk = 0; kk < 4; kk++)
                    #pragma unroll
                    for (int c = 0; c < 4; c++)
                        acc[j][c] = fmaf(xs[kk], wv[kk][c], acc[j][c]);
            }
        }
    }
    #pragma unroll
    for (int j = 0; j < 8; j++) {
        int gr = r0 + ty * 8 + j;
        if (gr < M)
            *(float4*)(H + (size_t)gr * 128 + tx * 4) =
                make_float4(acc[j][0], acc[j][1], acc[j][2], acc[j][3]);
    }
}

// ---------------------------------------------------------------------------
// Fused aggregation (CSR) + self-loop + bias + residual + LayerNorm.
// One 64-lane wave per node; each lane owns dims {lane, lane+64}.
// nid != nullptr  -> layer 1: h rows and residual rows are indexed via node_ids
//                    (h = h_emb [VOCAB x 128], resid = emb)
// nid == nullptr  -> layer 2: h = h2 [N x 128], resid = x1 (may alias out).
__global__ __launch_bounds__(256) void agg_ln(const int* __restrict__ row_ptr,
                                              const int* __restrict__ csr_src,
                                              const float* __restrict__ csr_w,
                                              const float* __restrict__ dis,
                                              const float* __restrict__ h,
                                              const int* __restrict__ nid,
                                              const float* resid,
                                              const float* __restrict__ bias,
                                              const float* __restrict__ gamma,
                                              const float* __restrict__ beta,
                                              float* out, int n) {
    int wave = (blockIdx.x * 256 + threadIdx.x) >> 6;
    int lane = threadIdx.x & 63;
    if (wave >= n) return;
    int i = wave;
    int hri = nid ? nid[i] : i;
    const float* hi = h + (size_t)hri * DIM;
    float dl = dis[i];
    float wself = dl * dl;                 // self-loop norm = dis[i]^2
    float acc0 = wself * hi[lane];
    float acc1 = wself * hi[64 + lane];
    int e0 = row_ptr[i], e1 = row_ptr[i + 1];
    for (int j = e0; j < e1; ++j) {
        int s = csr_src[j];
        float w = csr_w[j];
        int hr = nid ? nid[s] : s;
        const float* hs = h + (size_t)hr * DIM;
        acc0 += w * hs[lane];
        acc1 += w * hs[64 + lane];
    }
    const float* xr = resid + (size_t)hri * DIM;  // hri == i when nid==nullptr
    float v0 = xr[lane]      + acc0 + bias[lane];
    float v1 = xr[64 + lane] + acc1 + bias[64 + lane];
    // LayerNorm over 128 dims (2 per lane), wave butterfly reduction
    float s1 = v0 + v1, s2 = v0 * v0 + v1 * v1;
    #pragma unroll
    for (int o = 32; o > 0; o >>= 1) {
        s1 += __shfl_xor(s1, o, 64);
        s2 += __shfl_xor(s2, o, 64);
    }
    float mu   = s1 * (1.0f / DIM);
    float var  = s2 * (1.0f / DIM) - mu * mu;
    float rstd = rsqrtf(var + LN_EPS);
    out[(size_t)i * DIM + lane]      = (v0 - mu) * rstd * gamma[lane]      + beta[lane];
    out[(size_t)i * DIM + 64 + lane] = (v1 - mu) * rstd * gamma[64 + lane] + beta[64 + lane];
}

// ---------------------------------------------------------------------------
extern "C" void kernel_launch(void* const* d_in, const int* in_sizes, int n_in,
                              void* d_out, int out_size, void* d_ws, size_t ws_size,
                              hipStream_t stream) {
    const int*   node_ids = (const int*)  d_in[0];
    const int*   ei       = (const int*)  d_in[1];   // [2, E]
    const float* ew       = (const float*)d_in[2];
    const float* emb      = (const float*)d_in[3];   // [VOCAB, 128]
    const float* W1       = (const float*)d_in[4];
    const float* b1       = (const float*)d_in[5];
    const float* W2       = (const float*)d_in[6];
    const float* b2       = (const float*)d_in[7];
    const float* g1       = (const float*)d_in[8];
    const float* be1      = (const float*)d_in[9];
    const float* g2       = (const float*)d_in[10];
    const float* be2      = (const float*)d_in[11];
    float* out = (float*)d_out;

    // workspace carve-out (256B aligned), total ~31.5 MB
    char* p = (char*)d_ws;
    auto alloc = [&](size_t bytes) {
        char* r = p;
        p += (bytes + 255) & ~(size_t)255;
        return r;
    };
    float* h2      = (float*)alloc((size_t)N_NODES * DIM * 4);  // 25.6 MB
    float* h_emb   = (float*)alloc((size_t)VOCAB * DIM * 4);    // 256 KB
    float* degf    = (float*)alloc((size_t)N_NODES * 4);
    float* disv    = (float*)alloc((size_t)N_NODES * 4);
    int*   cnt     = (int*)  alloc((size_t)N_NODES * 4);
    int*   row_ptr = (int*)  alloc((size_t)(N_NODES + 1) * 4);
    int*   fill    = (int*)  alloc((size_t)N_NODES * 4);
    int*   bsum    = (int*)  alloc(64 * 4);
    int*   bofs    = (int*)  alloc(64 * 4);
    int*   csr_src = (int*)  alloc((size_t)N_EDGES * 4);        // 2.4 MB
    float* csr_w   = (float*)alloc((size_t)N_EDGES * 4);        // 2.4 MB

    int nb = (N_NODES + 1023) / 1024;  // 49

    // --- CSR + normalization build (shared by both layers) ---
    init_kernel<<<(N_NODES + 255) / 256, 256, 0, stream>>>(degf, cnt, N_NODES);
    deg_count_kernel<<<(N_EDGES + 255) / 256, 256, 0, stream>>>(ei, ew, degf, cnt, N_EDGES);
    scan_a<<<nb, 1024, 0, stream>>>(cnt, degf, disv, row_ptr, bsum, N_NODES);
    scan_b<<<1, 64, 0, stream>>>(bsum, bofs, nb);
    scan_c<<<nb, 1024, 0, stream>>>(row_ptr, fill, bofs, N_NODES, N_EDGES);
    scatter_kernel<<<(N_EDGES + 255) / 256, 256, 0, stream>>>(ei, ew, disv, fill,
                                                              csr_src, csr_w, N_EDGES);

    // --- Layer 1: x@W1 == (emb@W1)[node_ids]  -> only a 512-row matmul ---
    matmul128<<<(VOCAB + 63) / 64, 256, 0, stream>>>(emb, W1, h_emb, VOCAB);
    agg_ln<<<(N_NODES + 3) / 4, 256, 0, stream>>>(row_ptr, csr_src, csr_w, disv,
                                                  h_emb, node_ids, emb,
                                                  b1, g1, be1, out, N_NODES);

    // --- Layer 2: real 50000-row matmul, then fused agg+LN into d_out ---
    matmul128<<<(N_NODES + 63) / 64, 256, 0, stream>>>(out, W2, h2, N_NODES);
    agg_ln<<<(N_NODES + 3) / 4, 256, 0, stream>>>(row_ptr, csr_src, csr_w, disv,
                                                  h2, nullptr, out,
                                                  b2, g2, be2, out, N_NODES);
}

// Round 2
// 325.424 us; speedup vs baseline: 1.0979x; 1.0979x over previous
//
#include <hip/hip_runtime.h>

#define N_NODES 50000
#define N_EDGES 600000
#define DIM     128
#define VOCAB   512
#define LN_EPS  1e-5f

typedef unsigned int uint;

// round-to-nearest-even fp32 -> bf16 (as uint16 in low bits)
__device__ __forceinline__ uint f2bf(float f) {
    uint u = __float_as_uint(f);
    return (u + 0x7fffu + ((u >> 16) & 1u)) >> 16;
}
__device__ __forceinline__ float bf_lo(uint p) { return __uint_as_float(p << 16); }
__device__ __forceinline__ float bf_hi(uint p) { return __uint_as_float(p & 0xffff0000u); }

// ---------------------------------------------------------------------------
// K0: init degree (self-loop weight 1.0) and per-dst edge counts
__global__ void init_kernel(float* degf, int* cnt, int n) {
    int i = blockIdx.x * blockDim.x + threadIdx.x;
    if (i < n) { degf[i] = 1.0f; cnt[i] = 0; }
}

// K1: accumulate weighted in-degree and edge counts per destination
__global__ void deg_count_kernel(const int* __restrict__ ei, const float* __restrict__ ew,
                                 float* degf, int* cnt, int E) {
    int e = blockIdx.x * blockDim.x + threadIdx.x;
    if (e < E) {
        int c = ei[E + e];                 // edge_index[1][e] = destination
        atomicAdd(&degf[c], ew[e]);
        atomicAdd(&cnt[c], 1);
    }
}

// K2a: per-block exclusive scan of cnt (chunk of 1024) + dis = rsqrt(deg)
__global__ void scan_a(const int* __restrict__ cnt, const float* __restrict__ degf,
                       float* dis, int* row_ptr, int* bsum, int n) {
    __shared__ int sd[1024];
    int t = threadIdx.x;
    int i = blockIdx.x * 1024 + t;
    int v = (i < n) ? cnt[i] : 0;
    if (i < n) dis[i] = rsqrtf(degf[i]);   // deg >= 1 always (self loop)
    sd[t] = v;
    __syncthreads();
    for (int off = 1; off < 1024; off <<= 1) {
        int add = (t >= off) ? sd[t - off] : 0;
        __syncthreads();
        sd[t] += add;
        __syncthreads();
    }
    if (i < n) row_ptr[i] = sd[t] - v;     // block-local exclusive
    if (t == 1023) bsum[blockIdx.x] = sd[t];
}

// K2b: scan the (<=64) block sums
__global__ void scan_b(const int* __restrict__ bsum, int* bofs, int nb) {
    int t = threadIdx.x;                   // 64 threads, 1 wave
    int v = (t < nb) ? bsum[t] : 0;
    int incl = v;
    #pragma unroll
    for (int off = 1; off < 64; off <<= 1) {
        int up = __shfl_up(incl, off, 64);
        if (t >= off) incl += up;
    }
    if (t < nb) bofs[t] = incl - v;
}

// K2c: add block offsets -> final row_ptr; copy to fill cursor
__global__ void scan_c(int* row_ptr, int* fill, const int* __restrict__ bofs, int n, int E) {
    int i = blockIdx.x * 1024 + threadIdx.x;
    if (i < n) {
        int rp = row_ptr[i] + bofs[blockIdx.x];
        row_ptr[i] = rp;
        fill[i] = rp;
    }
    if (i == 0) row_ptr[n] = E;
}

// K3: scatter edges into CSR buckets.
// e2pack[pos] = {src, w}           (layer-2 gather rows index h2 directly)
// e1pack[pos] = {node_ids[src], w} (layer-1 gather rows index h_emb: resolves
//                                   the double indirection at build time)
__global__ void scatter_kernel(const int* __restrict__ ei, const float* __restrict__ ew,
                               const float* __restrict__ dis, const int* __restrict__ nid,
                               int* fill, int2* e1pack, int2* e2pack, int E) {
    int e = blockIdx.x * blockDim.x + threadIdx.x;
    if (e < E) {
        int s = ei[e];                     // source
        int c = ei[E + e];                 // destination
        int pos = atomicAdd(&fill[c], 1);
        int wbits = __float_as_int(dis[s] * ew[e] * dis[c]);
        e2pack[pos] = make_int2(s, wbits);
        e1pack[pos] = make_int2(nid[s], wbits);
    }
}

// ---------------------------------------------------------------------------
// Tiled fp32 matmul: Hb[M x 128 bf16x2-packed] = X[M x 128 fp32] @ W[128 x 128]
// block = 256 threads, 64-row output tile, K staged in chunks of 32.
// thread (tx = tid&31, ty = tid>>5) owns 8 rows x 4 cols.
__global__ __launch_bounds__(256) void matmul128(const float* __restrict__ X,
                                                 const float* __restrict__ W,
                                                 uint* __restrict__ Hb, int M) {
    __shared__ float Wt[32 * 128];         // 16 KB
    __shared__ float Xt[64 * 36];          // 9 KB (pad 32 -> 36 floats/row)
    int tid = threadIdx.x;
    int tx = tid & 31, ty = tid >> 5;
    int r0 = blockIdx.x * 64;
    float acc[8][4];
    #pragma unroll
    for (int j = 0; j < 8; j++)
        #pragma unroll
        for (int c = 0; c < 4; c++) acc[j][c] = 0.f;

    for (int kb = 0; kb < 128; kb += 32) {
        __syncthreads();
        #pragma unroll
        for (int q = 0; q < 4; q++) {
            int f = q * 256 + tid;         // float4 index 0..1023
            ((float4*)Wt)[f] = *(const float4*)(W + kb * 128 + f * 4);
        }
        #pragma unroll
        for (int q = 0; q < 2; q++) {
            int f = q * 256 + tid;         // 0..511
            int row = f >> 3, cs = f & 7;
            int gr = r0 + row;
            float4 xv = make_float4(0.f, 0.f, 0.f, 0.f);
            if (gr < M) xv = *(const float4*)(X + (size_t)gr * 128 + kb + cs * 4);
            *(float4*)(Xt + row * 36 + cs * 4) = xv;
        }
        __syncthreads();
        #pragma unroll
        for (int k = 0; k < 32; k += 4) {
            float wv[4][4];
            #pragma unroll
            for (int kk = 0; kk < 4; kk++) {
                float4 t4 = *(const float4*)(Wt + (k + kk) * 128 + tx * 4);
                wv[kk][0] = t4.x; wv[kk][1] = t4.y; wv[kk][2] = t4.z; wv[kk][3] = t4.w;
            }
            #pragma unroll
            for (int j = 0; j < 8; j++) {
                float4 xv = *(const float4*)(Xt + (ty * 8 + j) * 36 + k);
                float xs[4] = {xv.x, xv.y, xv.z, xv.w};
                #pragma unroll
                for (int kk = 0; kk < 4; kk++)
                    #pragma unroll
                    for (int c = 0; c < 4; c++)
                        acc[j][c] = fmaf(xs[kk], wv[kk][c], acc[j][c]);
            }
        }
    }
    #pragma unroll
    for (int j = 0; j < 8; j++) {
        int gr = r0 + ty * 8 + j;
        if (gr < M) {
            uint p0 = f2bf(acc[j][0]) | (f2bf(acc[j][1]) << 16);
            uint p1 = f2bf(acc[j][2]) | (f2bf(acc[j][3]) << 16);
            ((uint2*)Hb)[(size_t)gr * 32 + tx] = make_uint2(p0, p1);
        }
    }
}

// ---------------------------------------------------------------------------
// Fused aggregation (CSR, bf16 gather operand) + self-loop + bias + residual
// + LayerNorm. One 64-lane wave per node; lane owns dims {2*lane, 2*lane+1}.
// epack[j] = {h_row, w_bits}. nid: layer 1 -> self/resid row = nid[i];
// layer 2 -> nullptr (identity).
__global__ __launch_bounds__(256) void agg_ln(const int* __restrict__ row_ptr,
                                              const int2* __restrict__ epack,
                                              const float* __restrict__ dis,
                                              const uint* __restrict__ hb,
                                              const int* __restrict__ nid,
                                              const float* resid,
                                              const float* __restrict__ bias,
                                              const float* __restrict__ gamma,
                                              const float* __restrict__ beta,
                                              float* out, int n) {
    int i = (blockIdx.x * 256 + threadIdx.x) >> 6;
    int lane = threadIdx.x & 63;
    if (i >= n) return;
    int hri = nid ? nid[i] : i;
    float dl = dis[i];
    float wself = dl * dl;                 // self-loop norm = dis[i]^2
    uint ps = hb[(size_t)hri * 64 + lane];
    float acc0 = wself * bf_lo(ps);
    float acc1 = wself * bf_hi(ps);
    int e0 = row_ptr[i], e1 = row_ptr[i + 1];
    int2 nxt = (e0 < e1) ? epack[e0] : make_int2(0, 0);
    for (int j = e0; j < e1; ++j) {
        int2 cur = nxt;
        if (j + 1 < e1) nxt = epack[j + 1];          // prefetch next edge record
        float w = __int_as_float(cur.y);
        uint p = hb[(size_t)cur.x * 64 + lane];      // 256 B/wave gather
        acc0 += w * bf_lo(p);
        acc1 += w * bf_hi(p);
    }
    float2 xr = ((const float2*)resid)[(size_t)hri * 64 + lane];
    float2 bi = ((const float2*)bias)[lane];
    float v0 = xr.x + acc0 + bi.x;
    float v1 = xr.y + acc1 + bi.y;
    // LayerNorm over 128 dims (2 per lane), wave butterfly reduction
    float s1 = v0 + v1, s2 = v0 * v0 + v1 * v1;
    #pragma unroll
    for (int o = 32; o > 0; o >>= 1) {
        s1 += __shfl_xor(s1, o, 64);
        s2 += __shfl_xor(s2, o, 64);
    }
    float mu   = s1 * (1.0f / DIM);
    float var  = s2 * (1.0f / DIM) - mu * mu;
    float rstd = rsqrtf(var + LN_EPS);
    float2 ga = ((const float2*)gamma)[lane];
    float2 be = ((const float2*)beta)[lane];
    ((float2*)out)[(size_t)i * 64 + lane] =
        make_float2((v0 - mu) * rstd * ga.x + be.x,
                    (v1 - mu) * rstd * ga.y + be.y);
}

// ---------------------------------------------------------------------------
extern "C" void kernel_launch(void* const* d_in, const int* in_sizes, int n_in,
                              void* d_out, int out_size, void* d_ws, size_t ws_size,
                              hipStream_t stream) {
    const int*   node_ids = (const int*)  d_in[0];
    const int*   ei       = (const int*)  d_in[1];   // [2, E]
    const float* ew       = (const float*)d_in[2];
    const float* emb      = (const float*)d_in[3];   // [VOCAB, 128]
    const float* W1       = (const float*)d_in[4];
    const float* b1       = (const float*)d_in[5];
    const float* W2       = (const float*)d_in[6];
    const float* b2       = (const float*)d_in[7];
    const float* g1       = (const float*)d_in[8];
    const float* be1      = (const float*)d_in[9];
    const float* g2       = (const float*)d_in[10];
    const float* be2      = (const float*)d_in[11];
    float* out = (float*)d_out;

    // workspace carve-out (256B aligned), total ~24 MB
    char* p = (char*)d_ws;
    auto alloc = [&](size_t bytes) {
        char* r = p;
        p += (bytes + 255) & ~(size_t)255;
        return r;
    };
    uint*  h2b     = (uint*) alloc((size_t)N_NODES * 64 * 4);   // 12.8 MB bf16x2
    uint*  hembB   = (uint*) alloc((size_t)VOCAB * 64 * 4);     // 128 KB bf16x2
    float* degf    = (float*)alloc((size_t)N_NODES * 4);
    float* disv    = (float*)alloc((size_t)N_NODES * 4);
    int*   cnt     = (int*)  alloc((size_t)N_NODES * 4);
    int*   row_ptr = (int*)  alloc((size_t)(N_NODES + 1) * 4);
    int*   fill    = (int*)  alloc((size_t)N_NODES * 4);
    int*   bsum    = (int*)  alloc(64 * 4);
    int*   bofs    = (int*)  alloc(64 * 4);
    int2*  e1pack  = (int2*) alloc((size_t)N_EDGES * 8);        // 4.8 MB
    int2*  e2pack  = (int2*) alloc((size_t)N_EDGES * 8);        // 4.8 MB

    int nb = (N_NODES + 1023) / 1024;  // 49

    // --- CSR + normalization build (shared by both layers) ---
    init_kernel<<<(N_NODES + 255) / 256, 256, 0, stream>>>(degf, cnt, N_NODES);
    deg_count_kernel<<<(N_EDGES + 255) / 256, 256, 0, stream>>>(ei, ew, degf, cnt, N_EDGES);
    scan_a<<<nb, 1024, 0, stream>>>(cnt, degf, disv, row_ptr, bsum, N_NODES);
    scan_b<<<1, 64, 0, stream>>>(bsum, bofs, nb);
    scan_c<<<nb, 1024, 0, stream>>>(row_ptr, fill, bofs, N_NODES, N_EDGES);
    scatter_kernel<<<(N_EDGES + 255) / 256, 256, 0, stream>>>(ei, ew, disv, node_ids,
                                                              fill, e1pack, e2pack, N_EDGES);

    // --- Layer 1: x@W1 == (emb@W1)[node_ids]  -> only a 512-row matmul ---
    matmul128<<<(VOCAB + 63) / 64, 256, 0, stream>>>(emb, W1, hembB, VOCAB);
    agg_ln<<<(N_NODES + 3) / 4, 256, 0, stream>>>(row_ptr, e1pack, disv,
                                                  hembB, node_ids, emb,
                                                  b1, g1, be1, out, N_NODES);

    // --- Layer 2: real 50000-row matmul, then fused agg+LN into d_out ---
    matmul128<<<(N_NODES + 63) / 64, 256, 0, stream>>>(out, W2, h2b, N_NODES);
    agg_ln<<<(N_NODES + 3) / 4, 256, 0, stream>>>(row_ptr, e2pack, disv,
                                                  h2b, nullptr, out,
                                                  b2, g2, be2, out, N_NODES);
}

// Round 3
// 274.443 us; speedup vs baseline: 1.3018x; 1.1858x over previous
//
#include <hip/hip_runtime.h>

#define N_NODES 50000
#define N_EDGES 600000
#define DIM     128
#define VOCAB   512
#define LN_EPS  1e-5f
#define FIXS    16777216.0f   // 2^24 fixed-point scale for weight sums

typedef unsigned int uint;
typedef unsigned long long ull;

// round-to-nearest-even fp32 -> bf16 (as uint16 in low bits)
__device__ __forceinline__ uint f2bf(float f) {
    uint u = __float_as_uint(f);
    return (u + 0x7fffu + ((u >> 16) & 1u)) >> 16;
}
__device__ __forceinline__ float bf_lo(uint p) { return __uint_as_float(p << 16); }
__device__ __forceinline__ float bf_hi(uint p) { return __uint_as_float(p & 0xffff0000u); }

// ---------------------------------------------------------------------------
// K1: single 64-bit atomic per edge accumulates {count, fixed-point weight sum}
// per destination; returned old count = rank of this edge within its bucket.
// ILP=2: each thread handles two independent edges (E is even).
__global__ void deg_rank_kernel(const int* __restrict__ ei, const float* __restrict__ ew,
                                ull* pack, int* __restrict__ rank, int E) {
    int t = blockIdx.x * blockDim.x + threadIdx.x;
    int e0 = t * 2;
    if (e0 >= E) return;
    int   c0 = ei[E + e0],     c1 = ei[E + e0 + 1];
    float w0 = ew[e0],         w1 = ew[e0 + 1];
    ull a0 = (1ull << 32) | (ull)(uint)__float2int_rn(w0 * FIXS);
    ull a1 = (1ull << 32) | (ull)(uint)__float2int_rn(w1 * FIXS);
    ull r0 = atomicAdd(&pack[c0], a0);     // two independent chains in flight
    ull r1 = atomicAdd(&pack[c1], a1);
    rank[e0]     = (int)(r0 >> 32);
    rank[e0 + 1] = (int)(r1 >> 32);
}

// K2a: per-block exclusive scan of counts (chunk of 1024) + dis = rsqrt(1+deg)
__global__ void scan_a(const ull* __restrict__ pack,
                       float* dis, int* row_ptr, int* bsum, int n) {
    __shared__ int sd[1024];
    int t = threadIdx.x;
    int i = blockIdx.x * 1024 + t;
    int v = 0;
    if (i < n) {
        ull pv = pack[i];
        v = (int)(pv >> 32);
        dis[i] = rsqrtf(1.0f + (float)(uint)(pv & 0xffffffffu) * (1.0f / FIXS));
    }
    sd[t] = v;
    __syncthreads();
    for (int off = 1; off < 1024; off <<= 1) {
        int add = (t >= off) ? sd[t - off] : 0;
        __syncthreads();
        sd[t] += add;
        __syncthreads();
    }
    if (i < n) row_ptr[i] = sd[t] - v;     // block-local exclusive
    if (t == 1023) bsum[blockIdx.x] = sd[t];
}

// K2b: scan the (<=64) block sums
__global__ void scan_b(const int* __restrict__ bsum, int* bofs, int nb) {
    int t = threadIdx.x;                   // 64 threads, 1 wave
    int v = (t < nb) ? bsum[t] : 0;
    int incl = v;
    #pragma unroll
    for (int off = 1; off < 64; off <<= 1) {
        int up = __shfl_up(incl, off, 64);
        if (t >= off) incl += up;
    }
    if (t < nb) bofs[t] = incl - v;
}

// K2c: add block offsets -> final row_ptr
__global__ void scan_c(int* row_ptr, const int* __restrict__ bofs, int n, int E) {
    int i = blockIdx.x * 1024 + threadIdx.x;
    if (i < n) row_ptr[i] += bofs[blockIdx.x];
    if (i == 0) row_ptr[n] = E;
}

// K3: atomic-free CSR scatter. pos = row_ptr[dst] + rank[e].
// Record packs both layers' gather rows: bits 0-15 = src (layer 2 row into h2),
// bits 16-24 = node_ids[src] (layer 1 row into h_emb). w' = dis[src]*ew
// (dis[dst] is wave-uniform in agg and applied there).
__global__ void scatter_kernel(const int* __restrict__ ei, const float* __restrict__ ew,
                               const float* __restrict__ dis, const int* __restrict__ nid,
                               const int* __restrict__ row_ptr, const int* __restrict__ rank,
                               int2* __restrict__ epack, int E) {
    int e = blockIdx.x * blockDim.x + threadIdx.x;
    if (e < E) {
        int s = ei[e];
        int c = ei[E + e];
        int pos = row_ptr[c] + rank[e];
        uint ids = (uint)s | ((uint)nid[s] << 16);
        float wp = dis[s] * ew[e];
        epack[pos] = make_int2((int)ids, __float_as_int(wp));
    }
}

// ---------------------------------------------------------------------------
// Tiled fp32 matmul: Hb[M x 128 bf16x2-packed] = X[M x 128 fp32] @ W[128 x 128]
__global__ __launch_bounds__(256) void matmul128(const float* __restrict__ X,
                                                 const float* __restrict__ W,
                                                 uint* __restrict__ Hb, int M) {
    __shared__ float Wt[32 * 128];         // 16 KB
    __shared__ float Xt[64 * 36];          // 9 KB (pad 32 -> 36 floats/row)
    int tid = threadIdx.x;
    int tx = tid & 31, ty = tid >> 5;
    int r0 = blockIdx.x * 64;
    float acc[8][4];
    #pragma unroll
    for (int j = 0; j < 8; j++)
        #pragma unroll
        for (int c = 0; c < 4; c++) acc[j][c] = 0.f;

    for (int kb = 0; kb < 128; kb += 32) {
        __syncthreads();
        #pragma unroll
        for (int q = 0; q < 4; q++) {
            int f = q * 256 + tid;         // float4 index 0..1023
            ((float4*)Wt)[f] = *(const float4*)(W + kb * 128 + f * 4);
        }
        #pragma unroll
        for (int q = 0; q < 2; q++) {
            int f = q * 256 + tid;         // 0..511
            int row = f >> 3, cs = f & 7;
            int gr = r0 + row;
            float4 xv = make_float4(0.f, 0.f, 0.f, 0.f);
            if (gr < M) xv = *(const float4*)(X + (size_t)gr * 128 + kb + cs * 4);
            *(float4*)(Xt + row * 36 + cs * 4) = xv;
        }
        __syncthreads();
        #pragma unroll
        for (int k = 0; k < 32; k += 4) {
            float wv[4][4];
            #pragma unroll
            for (int kk = 0; kk < 4; kk++) {
                float4 t4 = *(const float4*)(Wt + (k + kk) * 128 + tx * 4);
                wv[kk][0] = t4.x; wv[kk][1] = t4.y; wv[kk][2] = t4.z; wv[kk][3] = t4.w;
            }
            #pragma unroll
            for (int j = 0; j < 8; j++) {
                float4 xv = *(const float4*)(Xt + (ty * 8 + j) * 36 + k);
                float xs[4] = {xv.x, xv.y, xv.z, xv.w};
                #pragma unroll
                for (int kk = 0; kk < 4; kk++)
                    #pragma unroll
                    for (int c = 0; c < 4; c++)
                        acc[j][c] = fmaf(xs[kk], wv[kk][c], acc[j][c]);
            }
        }
    }
    #pragma unroll
    for (int j = 0; j < 8; j++) {
        int gr = r0 + ty * 8 + j;
        if (gr < M) {
            uint p0 = f2bf(acc[j][0]) | (f2bf(acc[j][1]) << 16);
            uint p1 = f2bf(acc[j][2]) | (f2bf(acc[j][3]) << 16);
            ((uint2*)Hb)[(size_t)gr * 32 + tx] = make_uint2(p0, p1);
        }
    }
}

// ---------------------------------------------------------------------------
// Fused aggregation (CSR, bf16 gather operand) + self-loop + bias + residual
// + LayerNorm. One 64-lane wave per node; lane owns dims {2*lane, 2*lane+1}.
// Gather row = (epack.x >> shift) & 0xffff  (shift=0: layer 2, shift=16: layer 1).
// Edge weights are pre-divided by dis[dst]; the wave-uniform dl is applied once.
__global__ __launch_bounds__(256) void agg_ln(const int* __restrict__ row_ptr,
                                              const int2* __restrict__ epack,
                                              const float* __restrict__ dis,
                                              const uint* __restrict__ hb,
                                              const int* __restrict__ nid,
                                              const float* resid,
                                              const float* __restrict__ bias,
                                              const float* __restrict__ gamma,
                                              const float* __restrict__ beta,
                                              float* out, int n, int shift) {
    int i = (blockIdx.x * 256 + threadIdx.x) >> 6;
    int lane = threadIdx.x & 63;
    if (i >= n) return;
    int hri = nid ? nid[i] : i;
    float dl = dis[i];
    uint ps = hb[(size_t)hri * 64 + lane];
    float acc0 = dl * bf_lo(ps);           // self-loop; final *dl gives dl^2
    float acc1 = dl * bf_hi(ps);
    int e0 = row_ptr[i], e1 = row_ptr[i + 1];
    int2 nxt = (e0 < e1) ? epack[e0] : make_int2(0, 0);
    for (int j = e0; j < e1; ++j) {
        int2 cur = nxt;
        if (j + 1 < e1) nxt = epack[j + 1];              // prefetch next record
        float w = __int_as_float(cur.y);
        uint row = ((uint)cur.x >> shift) & 0xffffu;
        uint p = hb[(size_t)row * 64 + lane];            // 256 B/wave gather
        acc0 += w * bf_lo(p);
        acc1 += w * bf_hi(p);
    }
    float2 xr = ((const float2*)resid)[(size_t)hri * 64 + lane];
    float2 bi = ((const float2*)bias)[lane];
    float v0 = xr.x + dl * acc0 + bi.x;
    float v1 = xr.y + dl * acc1 + bi.y;
    // LayerNorm over 128 dims (2 per lane), wave butterfly reduction
    float s1 = v0 + v1, s2 = v0 * v0 + v1 * v1;
    #pragma unroll
    for (int o = 32; o > 0; o >>= 1) {
        s1 += __shfl_xor(s1, o, 64);
        s2 += __shfl_xor(s2, o, 64);
    }
    float mu   = s1 * (1.0f / DIM);
    float var  = s2 * (1.0f / DIM) - mu * mu;
    float rstd = rsqrtf(var + LN_EPS);
    float2 ga = ((const float2*)gamma)[lane];
    float2 be = ((const float2*)beta)[lane];
    ((float2*)out)[(size_t)i * 64 + lane] =
        make_float2((v0 - mu) * rstd * ga.x + be.x,
                    (v1 - mu) * rstd * ga.y + be.y);
}

// ---------------------------------------------------------------------------
extern "C" void kernel_launch(void* const* d_in, const int* in_sizes, int n_in,
                              void* d_out, int out_size, void* d_ws, size_t ws_size,
                              hipStream_t stream) {
    const int*   node_ids = (const int*)  d_in[0];
    const int*   ei       = (const int*)  d_in[1];   // [2, E]
    const float* ew       = (const float*)d_in[2];
    const float* emb      = (const float*)d_in[3];   // [VOCAB, 128]
    const float* W1       = (const float*)d_in[4];
    const float* b1       = (const float*)d_in[5];
    const float* W2       = (const float*)d_in[6];
    const float* b2       = (const float*)d_in[7];
    const float* g1       = (const float*)d_in[8];
    const float* be1      = (const float*)d_in[9];
    const float* g2       = (const float*)d_in[10];
    const float* be2      = (const float*)d_in[11];
    float* out = (float*)d_out;

    // workspace carve-out (256B aligned), total ~21 MB
    char* p = (char*)d_ws;
    auto alloc = [&](size_t bytes) {
        char* r = p;
        p += (bytes + 255) & ~(size_t)255;
        return r;
    };
    uint*  h2b     = (uint*) alloc((size_t)N_NODES * 64 * 4);   // 12.8 MB bf16x2
    uint*  hembB   = (uint*) alloc((size_t)VOCAB * 64 * 4);     // 128 KB bf16x2
    ull*   pack    = (ull*)  alloc((size_t)N_NODES * 8);        // 400 KB
    float* disv    = (float*)alloc((size_t)N_NODES * 4);
    int*   row_ptr = (int*)  alloc((size_t)(N_NODES + 1) * 4);
    int*   rank    = (int*)  alloc((size_t)N_EDGES * 4);        // 2.4 MB
    int*   bsum    = (int*)  alloc(64 * 4);
    int*   bofs    = (int*)  alloc(64 * 4);
    int2*  epack   = (int2*) alloc((size_t)N_EDGES * 8);        // 4.8 MB shared

    int nb = (N_NODES + 1023) / 1024;  // 49

    // --- CSR + normalization build (shared by both layers) ---
    hipMemsetAsync(pack, 0, (size_t)N_NODES * 8, stream);
    deg_rank_kernel<<<(N_EDGES / 2 + 255) / 256, 256, 0, stream>>>(ei, ew, pack, rank, N_EDGES);
    scan_a<<<nb, 1024, 0, stream>>>(pack, disv, row_ptr, bsum, N_NODES);
    scan_b<<<1, 64, 0, stream>>>(bsum, bofs, nb);
    scan_c<<<nb, 1024, 0, stream>>>(row_ptr, bofs, N_NODES, N_EDGES);
    scatter_kernel<<<(N_EDGES + 255) / 256, 256, 0, stream>>>(ei, ew, disv, node_ids,
                                                              row_ptr, rank, epack, N_EDGES);

    // --- Layer 1: x@W1 == (emb@W1)[node_ids]  -> only a 512-row matmul ---
    matmul128<<<(VOCAB + 63) / 64, 256, 0, stream>>>(emb, W1, hembB, VOCAB);
    agg_ln<<<(N_NODES + 3) / 4, 256, 0, stream>>>(row_ptr, epack, disv,
                                                  hembB, node_ids, emb,
                                                  b1, g1, be1, out, N_NODES, 16);

    // --- Layer 2: real 50000-row matmul, then fused agg+LN into d_out ---
    matmul128<<<(N_NODES + 63) / 64, 256, 0, stream>>>(out, W2, h2b, N_NODES);
    agg_ln<<<(N_NODES + 3) / 4, 256, 0, stream>>>(row_ptr, epack, disv,
                                                  h2b, nullptr, out,
                                                  b2, g2, be2, out, N_NODES, 0);
}

// Round 4
// 252.186 us; speedup vs baseline: 1.4167x; 1.0883x over previous
//
#include <hip/hip_runtime.h>

#define N_NODES 50000
#define N_EDGES 600000
#define DIM     128
#define VOCAB   512
#define LN_EPS  1e-5f
#define FIXS    16777216.0f   // 2^24 fixed-point scale for weight sums

typedef unsigned int uint;
typedef unsigned long long ull;

// round-to-nearest-even fp32 -> bf16 (as uint16 in low bits)
__device__ __forceinline__ uint f2bf(float f) {
    uint u = __float_as_uint(f);
    return (u + 0x7fffu + ((u >> 16) & 1u)) >> 16;
}
__device__ __forceinline__ float bf_lo(uint p) { return __uint_as_float(p << 16); }
__device__ __forceinline__ float bf_hi(uint p) { return __uint_as_float(p & 0xffff0000u); }

// ---------------------------------------------------------------------------
// K1: single 64-bit atomic per edge accumulates {count, fixed-point weight sum}
// per destination; returned old count = rank of this edge within its bucket.
// ILP=4: four independent atomic chains per thread (E % 4 == 0).
__global__ void deg_rank_kernel(const int* __restrict__ ei, const float* __restrict__ ew,
                                ull* pack, int* __restrict__ rank, int E) {
    int e0 = (blockIdx.x * blockDim.x + threadIdx.x) * 4;
    if (e0 >= E) return;
    int4   c = *(const int4*)  (ei + E + e0);
    float4 w = *(const float4*)(ew + e0);
    ull a0 = (1ull << 32) | (ull)(uint)__float2int_rn(w.x * FIXS);
    ull a1 = (1ull << 32) | (ull)(uint)__float2int_rn(w.y * FIXS);
    ull a2 = (1ull << 32) | (ull)(uint)__float2int_rn(w.z * FIXS);
    ull a3 = (1ull << 32) | (ull)(uint)__float2int_rn(w.w * FIXS);
    ull r0 = atomicAdd(&pack[c.x], a0);
    ull r1 = atomicAdd(&pack[c.y], a1);
    ull r2 = atomicAdd(&pack[c.z], a2);
    ull r3 = atomicAdd(&pack[c.w], a3);
    *(int4*)(rank + e0) = make_int4((int)(r0 >> 32), (int)(r1 >> 32),
                                    (int)(r2 >> 32), (int)(r3 >> 32));
}

// K2a: per-block exclusive scan of counts (chunk of 1024) + dis = rsqrt(1+deg)
__global__ void scan_a(const ull* __restrict__ pack,
                       float* dis, int* row_ptr, int* bsum, int n) {
    __shared__ int sd[1024];
    int t = threadIdx.x;
    int i = blockIdx.x * 1024 + t;
    int v = 0;
    if (i < n) {
        ull pv = pack[i];
        v = (int)(pv >> 32);
        dis[i] = rsqrtf(1.0f + (float)(uint)(pv & 0xffffffffu) * (1.0f / FIXS));
    }
    sd[t] = v;
    __syncthreads();
    for (int off = 1; off < 1024; off <<= 1) {
        int add = (t >= off) ? sd[t - off] : 0;
        __syncthreads();
        sd[t] += add;
        __syncthreads();
    }
    if (i < n) row_ptr[i] = sd[t] - v;     // block-local exclusive
    if (t == 1023) bsum[blockIdx.x] = sd[t];
}

// K2b: scan the (<=64) block sums
__global__ void scan_b(const int* __restrict__ bsum, int* bofs, int nb) {
    int t = threadIdx.x;                   // 64 threads, 1 wave
    int v = (t < nb) ? bsum[t] : 0;
    int incl = v;
    #pragma unroll
    for (int off = 1; off < 64; off <<= 1) {
        int up = __shfl_up(incl, off, 64);
        if (t >= off) incl += up;
    }
    if (t < nb) bofs[t] = incl - v;
}

// K2c: add block offsets -> final row_ptr
__global__ void scan_c(int* row_ptr, const int* __restrict__ bofs, int n, int E) {
    int i = blockIdx.x * 1024 + threadIdx.x;
    if (i < n) row_ptr[i] += bofs[blockIdx.x];
    if (i == 0) row_ptr[n] = E;
}

// K3: atomic-free CSR scatter. pos = row_ptr[dst] + rank[e].
// Record packs both layers' gather rows: bits 0-15 = src (layer 2 row into h2),
// bits 16-24 = node_ids[src] (layer 1 row into h_emb). w' = dis[src]*ew
// (dis[dst] is wave-uniform in agg and applied there).
__global__ void scatter_kernel(const int* __restrict__ ei, const float* __restrict__ ew,
                               const float* __restrict__ dis, const int* __restrict__ nid,
                               const int* __restrict__ row_ptr, const int* __restrict__ rank,
                               int2* __restrict__ epack, int E) {
    int e = blockIdx.x * blockDim.x + threadIdx.x;
    if (e < E) {
        int s = ei[e];
        int c = ei[E + e];
        int pos = row_ptr[c] + rank[e];
        uint ids = (uint)s | ((uint)nid[s] << 16);
        float wp = dis[s] * ew[e];
        epack[pos] = make_int2((int)ids, __float_as_int(wp));
    }
}

// ---------------------------------------------------------------------------
// Tiled matmul: Hb[M x 128 bf16x2] = X[M x 128] @ W[128 x 128 fp32]
// XBF: X is bf16x2-packed (uint, 64/row); else fp32.
template<bool XBF>
__global__ __launch_bounds__(256) void matmul128(const void* __restrict__ Xv,
                                                 const float* __restrict__ W,
                                                 uint* __restrict__ Hb, int M) {
    __shared__ float Wt[32 * 128];         // 16 KB
    __shared__ float Xt[64 * 36];          // 9 KB (pad 32 -> 36 floats/row)
    int tid = threadIdx.x;
    int tx = tid & 31, ty = tid >> 5;
    int r0 = blockIdx.x * 64;
    float acc[8][4];
    #pragma unroll
    for (int j = 0; j < 8; j++)
        #pragma unroll
        for (int c = 0; c < 4; c++) acc[j][c] = 0.f;

    for (int kb = 0; kb < 128; kb += 32) {
        __syncthreads();
        #pragma unroll
        for (int q = 0; q < 4; q++) {
            int f = q * 256 + tid;         // float4 index 0..1023
            ((float4*)Wt)[f] = *(const float4*)(W + kb * 128 + f * 4);
        }
        #pragma unroll
        for (int q = 0; q < 2; q++) {
            int f = q * 256 + tid;         // 0..511
            int row = f >> 3, cs = f & 7;  // 64 rows x 8 4-dim chunks
            int gr = r0 + row;
            float4 xv = make_float4(0.f, 0.f, 0.f, 0.f);
            if (gr < M) {
                if (XBF) {
                    uint2 xp = *(const uint2*)((const uint*)Xv + (size_t)gr * 64 + kb / 2 + cs * 2);
                    xv = make_float4(bf_lo(xp.x), bf_hi(xp.x), bf_lo(xp.y), bf_hi(xp.y));
                } else {
                    xv = *(const float4*)((const float*)Xv + (size_t)gr * 128 + kb + cs * 4);
                }
            }
            *(float4*)(Xt + row * 36 + cs * 4) = xv;
        }
        __syncthreads();
        #pragma unroll
        for (int k = 0; k < 32; k += 4) {
            float wv[4][4];
            #pragma unroll
            for (int kk = 0; kk < 4; kk++) {
                float4 t4 = *(const float4*)(Wt + (k + kk) * 128 + tx * 4);
                wv[kk][0] = t4.x; wv[kk][1] = t4.y; wv[kk][2] = t4.z; wv[kk][3] = t4.w;
            }
            #pragma unroll
            for (int j = 0; j < 8; j++) {
                float4 xv = *(const float4*)(Xt + (ty * 8 + j) * 36 + k);
                float xs[4] = {xv.x, xv.y, xv.z, xv.w};
                #pragma unroll
                for (int kk = 0; kk < 4; kk++)
                    #pragma unroll
                    for (int c = 0; c < 4; c++)
                        acc[j][c] = fmaf(xs[kk], wv[kk][c], acc[j][c]);
            }
        }
    }
    #pragma unroll
    for (int j = 0; j < 8; j++) {
        int gr = r0 + ty * 8 + j;
        if (gr < M) {
            uint p0 = f2bf(acc[j][0]) | (f2bf(acc[j][1]) << 16);
            uint p1 = f2bf(acc[j][2]) | (f2bf(acc[j][3]) << 16);
            ((uint2*)Hb)[(size_t)gr * 32 + tx] = make_uint2(p0, p1);
        }
    }
}

// ---------------------------------------------------------------------------
// Fused aggregation (CSR, bf16 gather operand) + self-loop + bias + residual
// + LayerNorm. One 64-lane wave per node; lane owns dims {2*lane, 2*lane+1}.
// Gather row = (epack.x >> SHIFT) & 0xffff (0: layer 2, 16: layer 1).
// Gather loop unrolled x4: 4 independent row gathers in flight per iteration.
// RESID_BF: residual input is bf16x2-packed. OUT_BF: write bf16x2 (else fp32).
template<int SHIFT, bool RESID_BF, bool OUT_BF>
__global__ __launch_bounds__(256) void agg_ln(const int* __restrict__ row_ptr,
                                              const int2* __restrict__ epack,
                                              const float* __restrict__ dis,
                                              const uint* __restrict__ hb,
                                              const int* __restrict__ nid,
                                              const void* __restrict__ resid,
                                              const float* __restrict__ bias,
                                              const float* __restrict__ gamma,
                                              const float* __restrict__ beta,
                                              void* __restrict__ out, int n) {
    int i = (blockIdx.x * 256 + threadIdx.x) >> 6;
    int lane = threadIdx.x & 63;
    if (i >= n) return;
    int hri = nid ? nid[i] : i;
    float dl = dis[i];
    uint ps = hb[(size_t)hri * 64 + lane];
    float acc0 = dl * bf_lo(ps);           // self-loop; final *dl gives dl^2
    float acc1 = dl * bf_hi(ps);
    float c0 = 0.f, c1 = 0.f;              // second accumulator pair
    int e0 = row_ptr[i], e1 = row_ptr[i + 1];
    int j = e0;
    for (; j + 3 < e1; j += 4) {           // 4 gathers in flight
        int2 r0 = epack[j], r1 = epack[j + 1], r2 = epack[j + 2], r3 = epack[j + 3];
        uint q0 = hb[(size_t)(((uint)r0.x >> SHIFT) & 0xffffu) * 64 + lane];
        uint q1 = hb[(size_t)(((uint)r1.x >> SHIFT) & 0xffffu) * 64 + lane];
        uint q2 = hb[(size_t)(((uint)r2.x >> SHIFT) & 0xffffu) * 64 + lane];
        uint q3 = hb[(size_t)(((uint)r3.x >> SHIFT) & 0xffffu) * 64 + lane];
        float w0 = __int_as_float(r0.y), w1 = __int_as_float(r1.y);
        float w2 = __int_as_float(r2.y), w3 = __int_as_float(r3.y);
        acc0 += w0 * bf_lo(q0); acc1 += w0 * bf_hi(q0);
        c0   += w1 * bf_lo(q1); c1   += w1 * bf_hi(q1);
        acc0 += w2 * bf_lo(q2); acc1 += w2 * bf_hi(q2);
        c0   += w3 * bf_lo(q3); c1   += w3 * bf_hi(q3);
    }
    for (; j < e1; ++j) {
        int2 r = epack[j];
        float w = __int_as_float(r.y);
        uint q = hb[(size_t)(((uint)r.x >> SHIFT) & 0xffffu) * 64 + lane];
        acc0 += w * bf_lo(q); acc1 += w * bf_hi(q);
    }
    acc0 += c0; acc1 += c1;
    float2 xr;
    if (RESID_BF) {
        uint pr = ((const uint*)resid)[(size_t)hri * 64 + lane];
        xr = make_float2(bf_lo(pr), bf_hi(pr));
    } else {
        xr = ((const float2*)resid)[(size_t)hri * 64 + lane];
    }
    float2 bi = ((const float2*)bias)[lane];
    float v0 = xr.x + dl * acc0 + bi.x;
    float v1 = xr.y + dl * acc1 + bi.y;
    // LayerNorm over 128 dims (2 per lane), wave butterfly reduction
    float s1 = v0 + v1, s2 = v0 * v0 + v1 * v1;
    #pragma unroll
    for (int o = 32; o > 0; o >>= 1) {
        s1 += __shfl_xor(s1, o, 64);
        s2 += __shfl_xor(s2, o, 64);
    }
    float mu   = s1 * (1.0f / DIM);
    float var  = s2 * (1.0f / DIM) - mu * mu;
    float rstd = rsqrtf(var + LN_EPS);
    float2 ga = ((const float2*)gamma)[lane];
    float2 be = ((const float2*)beta)[lane];
    float o0 = (v0 - mu) * rstd * ga.x + be.x;
    float o1 = (v1 - mu) * rstd * ga.y + be.y;
    if (OUT_BF) {
        ((uint*)out)[(size_t)i * 64 + lane] = f2bf(o0) | (f2bf(o1) << 16);
    } else {
        ((float2*)out)[(size_t)i * 64 + lane] = make_float2(o0, o1);
    }
}

// ---------------------------------------------------------------------------
extern "C" void kernel_launch(void* const* d_in, const int* in_sizes, int n_in,
                              void* d_out, int out_size, void* d_ws, size_t ws_size,
                              hipStream_t stream) {
    const int*   node_ids = (const int*)  d_in[0];
    const int*   ei       = (const int*)  d_in[1];   // [2, E]
    const float* ew       = (const float*)d_in[2];
    const float* emb      = (const float*)d_in[3];   // [VOCAB, 128]
    const float* W1       = (const float*)d_in[4];
    const float* b1       = (const float*)d_in[5];
    const float* W2       = (const float*)d_in[6];
    const float* b2       = (const float*)d_in[7];
    const float* g1       = (const float*)d_in[8];
    const float* be1      = (const float*)d_in[9];
    const float* g2       = (const float*)d_in[10];
    const float* be2      = (const float*)d_in[11];
    float* out = (float*)d_out;

    // workspace carve-out (256B aligned), total ~34 MB
    char* p = (char*)d_ws;
    auto alloc = [&](size_t bytes) {
        char* r = p;
        p += (bytes + 255) & ~(size_t)255;
        return r;
    };
    uint*  h2b     = (uint*) alloc((size_t)N_NODES * 64 * 4);   // 12.8 MB bf16x2
    uint*  x1b     = (uint*) alloc((size_t)N_NODES * 64 * 4);   // 12.8 MB bf16x2 (LN1 out)
    uint*  hembB   = (uint*) alloc((size_t)VOCAB * 64 * 4);     // 128 KB bf16x2
    ull*   pack    = (ull*)  alloc((size_t)N_NODES * 8);        // 400 KB
    float* disv    = (float*)alloc((size_t)N_NODES * 4);
    int*   row_ptr = (int*)  alloc((size_t)(N_NODES + 1) * 4);
    int*   rank    = (int*)  alloc((size_t)N_EDGES * 4);        // 2.4 MB
    int*   bsum    = (int*)  alloc(64 * 4);
    int*   bofs    = (int*)  alloc(64 * 4);
    int2*  epack   = (int2*) alloc((size_t)N_EDGES * 8);        // 4.8 MB shared

    int nb = (N_NODES + 1023) / 1024;  // 49

    // --- CSR + normalization build (shared by both layers) ---
    hipMemsetAsync(pack, 0, (size_t)N_NODES * 8, stream);
    deg_rank_kernel<<<(N_EDGES / 4 + 255) / 256, 256, 0, stream>>>(ei, ew, pack, rank, N_EDGES);
    scan_a<<<nb, 1024, 0, stream>>>(pack, disv, row_ptr, bsum, N_NODES);
    scan_b<<<1, 64, 0, stream>>>(bsum, bofs, nb);
    scan_c<<<nb, 1024, 0, stream>>>(row_ptr, bofs, N_NODES, N_EDGES);
    scatter_kernel<<<(N_EDGES + 255) / 256, 256, 0, stream>>>(ei, ew, disv, node_ids,
                                                              row_ptr, rank, epack, N_EDGES);

    // --- Layer 1: x@W1 == (emb@W1)[node_ids]  -> only a 512-row matmul ---
    matmul128<false><<<(VOCAB + 63) / 64, 256, 0, stream>>>(emb, W1, hembB, VOCAB);
    // LN1 output -> bf16x2 workspace (x1b); resid = emb rows (fp32)
    agg_ln<16, false, true><<<(N_NODES + 3) / 4, 256, 0, stream>>>(
        row_ptr, epack, disv, hembB, node_ids, emb, b1, g1, be1, x1b, N_NODES);

    // --- Layer 2: 50000-row matmul on bf16 X, then fused agg+LN -> d_out ---
    matmul128<true><<<(N_NODES + 63) / 64, 256, 0, stream>>>(x1b, W2, h2b, N_NODES);
    agg_ln<0, true, false><<<(N_NODES + 3) / 4, 256, 0, stream>>>(
        row_ptr, epack, disv, h2b, nullptr, x1b, b2, g2, be2, out, N_NODES);
}

// Round 5
// 242.227 us; speedup vs baseline: 1.4749x; 1.0411x over previous
//
#include <hip/hip_runtime.h>

#define N_NODES 50000
#define N_EDGES 600000
#define DIM     128
#define VOCAB   512
#define LN_EPS  1e-5f
#define FIXS    16777216.0f   // 2^24 fixed-point scale for weight sums

typedef unsigned int uint;
typedef unsigned long long ull;
typedef unsigned short ushort;
typedef __attribute__((ext_vector_type(8))) short s8v;   // 8 bf16 (4 VGPRs)
typedef __attribute__((ext_vector_type(4))) float f4v;   // 4 fp32 acc

// round-to-nearest-even fp32 -> bf16 (as uint16 in low bits)
__device__ __forceinline__ uint f2bf(float f) {
    uint u = __float_as_uint(f);
    return (u + 0x7fffu + ((u >> 16) & 1u)) >> 16;
}
__device__ __forceinline__ float bf_lo(uint p) { return __uint_as_float(p << 16); }
__device__ __forceinline__ float bf_hi(uint p) { return __uint_as_float(p & 0xffff0000u); }

// ---------------------------------------------------------------------------
// K1: single 64-bit atomic per edge accumulates {count, fixed-point weight sum}
// per destination; returned old count = rank of this edge within its bucket.
__global__ void deg_rank_kernel(const int* __restrict__ ei, const float* __restrict__ ew,
                                ull* pack, int* __restrict__ rank, int E) {
    int e0 = (blockIdx.x * blockDim.x + threadIdx.x) * 4;
    if (e0 >= E) return;
    int4   c = *(const int4*)  (ei + E + e0);
    float4 w = *(const float4*)(ew + e0);
    ull a0 = (1ull << 32) | (ull)(uint)__float2int_rn(w.x * FIXS);
    ull a1 = (1ull << 32) | (ull)(uint)__float2int_rn(w.y * FIXS);
    ull a2 = (1ull << 32) | (ull)(uint)__float2int_rn(w.z * FIXS);
    ull a3 = (1ull << 32) | (ull)(uint)__float2int_rn(w.w * FIXS);
    ull r0 = atomicAdd(&pack[c.x], a0);
    ull r1 = atomicAdd(&pack[c.y], a1);
    ull r2 = atomicAdd(&pack[c.z], a2);
    ull r3 = atomicAdd(&pack[c.w], a3);
    *(int4*)(rank + e0) = make_int4((int)(r0 >> 32), (int)(r1 >> 32),
                                    (int)(r2 >> 32), (int)(r3 >> 32));
}

// K2a: per-block exclusive scan of counts (chunk of 1024) + dis = rsqrt(1+deg)
__global__ void scan_a(const ull* __restrict__ pack,
                       float* dis, int* row_ptr, int* bsum, int n) {
    __shared__ int sd[1024];
    int t = threadIdx.x;
    int i = blockIdx.x * 1024 + t;
    int v = 0;
    if (i < n) {
        ull pv = pack[i];
        v = (int)(pv >> 32);
        dis[i] = rsqrtf(1.0f + (float)(uint)(pv & 0xffffffffu) * (1.0f / FIXS));
    }
    sd[t] = v;
    __syncthreads();
    for (int off = 1; off < 1024; off <<= 1) {
        int add = (t >= off) ? sd[t - off] : 0;
        __syncthreads();
        sd[t] += add;
        __syncthreads();
    }
    if (i < n) row_ptr[i] = sd[t] - v;     // block-local exclusive
    if (t == 1023) bsum[blockIdx.x] = sd[t];
}

// K2b: scan the (<=64) block sums
__global__ void scan_b(const int* __restrict__ bsum, int* bofs, int nb) {
    int t = threadIdx.x;                   // 64 threads, 1 wave
    int v = (t < nb) ? bsum[t] : 0;
    int incl = v;
    #pragma unroll
    for (int off = 1; off < 64; off <<= 1) {
        int up = __shfl_up(incl, off, 64);
        if (t >= off) incl += up;
    }
    if (t < nb) bofs[t] = incl - v;
}

// K2c: add block offsets -> final row_ptr
__global__ void scan_c(int* row_ptr, const int* __restrict__ bofs, int n, int E) {
    int i = blockIdx.x * 1024 + threadIdx.x;
    if (i < n) row_ptr[i] += bofs[blockIdx.x];
    if (i == 0) row_ptr[n] = E;
}

// K3: atomic-free CSR scatter. pos = row_ptr[dst] + rank[e].
// Record: bits 0-15 = src (layer-2 row), bits 16-24 = node_ids[src] (layer-1
// row). w' = dis[src]*ew; dis[dst] is wave-uniform in agg, applied there.
__global__ void scatter_kernel(const int* __restrict__ ei, const float* __restrict__ ew,
                               const float* __restrict__ dis, const int* __restrict__ nid,
                               const int* __restrict__ row_ptr, const int* __restrict__ rank,
                               int2* __restrict__ epack, int E) {
    int e = blockIdx.x * blockDim.x + threadIdx.x;
    if (e < E) {
        int s = ei[e];
        int c = ei[E + e];
        int pos = row_ptr[c] + rank[e];
        uint ids = (uint)s | ((uint)nid[s] << 16);
        float wp = dis[s] * ew[e];
        epack[pos] = make_int2((int)ids, __float_as_int(wp));
    }
}

// ---------------------------------------------------------------------------
// K4: pre-pack W2 (fp32 128x128) into bf16 MFMA B-fragment order:
// Wp[((nc*4+kc)*64 + lane)*8 + j] = bf16(W[k][n]), k=kc*32+(lane>>4)*8+j,
// n=nc*16+(lane&15). One B-frag is then a contiguous 16B/lane load.
__global__ void prepack_w(const float* __restrict__ W, ushort* __restrict__ Wp) {
    int o = blockIdx.x * 256 + threadIdx.x;        // 0..16383
    int j = o & 7, lane = (o >> 3) & 63, chunk = o >> 9;
    int kc = chunk & 3, nc = chunk >> 2;
    int k = kc * 32 + (lane >> 4) * 8 + j;
    int n = nc * 16 + (lane & 15);
    Wp[o] = (ushort)f2bf(W[k * 128 + n]);
}

// ---------------------------------------------------------------------------
// Tiled fp32 matmul (layer 1 only, M=512): Hb = X[f32] @ W -> bf16x2
__global__ __launch_bounds__(256) void matmul128(const float* __restrict__ X,
                                                 const float* __restrict__ W,
                                                 uint* __restrict__ Hb, int M) {
    __shared__ float Wt[32 * 128];
    __shared__ float Xt[64 * 36];
    int tid = threadIdx.x;
    int tx = tid & 31, ty = tid >> 5;
    int r0 = blockIdx.x * 64;
    float acc[8][4];
    #pragma unroll
    for (int j = 0; j < 8; j++)
        #pragma unroll
        for (int c = 0; c < 4; c++) acc[j][c] = 0.f;

    for (int kb = 0; kb < 128; kb += 32) {
        __syncthreads();
        #pragma unroll
        for (int q = 0; q < 4; q++) {
            int f = q * 256 + tid;
            ((float4*)Wt)[f] = *(const float4*)(W + kb * 128 + f * 4);
        }
        #pragma unroll
        for (int q = 0; q < 2; q++) {
            int f = q * 256 + tid;
            int row = f >> 3, cs = f & 7;
            int gr = r0 + row;
            float4 xv = make_float4(0.f, 0.f, 0.f, 0.f);
            if (gr < M) xv = *(const float4*)(X + (size_t)gr * 128 + kb + cs * 4);
            *(float4*)(Xt + row * 36 + cs * 4) = xv;
        }
        __syncthreads();
        #pragma unroll
        for (int k = 0; k < 32; k += 4) {
            float wv[4][4];
            #pragma unroll
            for (int kk = 0; kk < 4; kk++) {
                float4 t4 = *(const float4*)(Wt + (k + kk) * 128 + tx * 4);
                wv[kk][0] = t4.x; wv[kk][1] = t4.y; wv[kk][2] = t4.z; wv[kk][3] = t4.w;
            }
            #pragma unroll
            for (int j = 0; j < 8; j++) {
                float4 xv = *(const float4*)(Xt + (ty * 8 + j) * 36 + k);
                float xs[4] = {xv.x, xv.y, xv.z, xv.w};
                #pragma unroll
                for (int kk = 0; kk < 4; kk++)
                    #pragma unroll
                    for (int c = 0; c < 4; c++)
                        acc[j][c] = fmaf(xs[kk], wv[kk][c], acc[j][c]);
            }
        }
    }
    #pragma unroll
    for (int j = 0; j < 8; j++) {
        int gr = r0 + ty * 8 + j;
        if (gr < M) {
            uint p0 = f2bf(acc[j][0]) | (f2bf(acc[j][1]) << 16);
            uint p1 = f2bf(acc[j][2]) | (f2bf(acc[j][3]) << 16);
            ((uint2*)Hb)[(size_t)gr * 32 + tx] = make_uint2(p0, p1);
        }
    }
}

// ---------------------------------------------------------------------------
// K5: MFMA bf16 matmul (layer 2): H[M x 128 bf16] = Xb[M x 128 bf16] @ W2.
// One wave per 16 rows; 8 n-chunks x 4 k-chunks of mfma_f32_16x16x32_bf16.
// A-frag: lane holds X[r0+(lane&15)][kc*32+(lane>>4)*8 .. +8] — exactly a
// contiguous uint4 of the bf16x2-packed row. B-frags from prepacked Wp (L1).
// C/D layout: row=(lane>>4)*4+reg, col=lane&15 [m89/m91-verified].
__global__ __launch_bounds__(256) void mm2_mfma(const uint* __restrict__ Xb,
                                                const ushort* __restrict__ Wp,
                                                ushort* __restrict__ H, int M) {
    int wid = (blockIdx.x * 256 + threadIdx.x) >> 6;
    int lane = threadIdx.x & 63;
    int r0 = wid * 16;
    if (r0 >= M) return;                    // M % 16 == 0: no partial tiles
    int quad = lane >> 4, lo = lane & 15;
    const uint* xrow = Xb + (size_t)(r0 + lo) * 64 + quad * 4;
    s8v a[4];
    #pragma unroll
    for (int kc = 0; kc < 4; kc++) a[kc] = *(const s8v*)(xrow + kc * 16);
    #pragma unroll
    for (int nc = 0; nc < 8; nc++) {
        f4v acc = {0.f, 0.f, 0.f, 0.f};
        #pragma unroll
        for (int kc = 0; kc < 4; kc++) {
            s8v b = *(const s8v*)(Wp + (size_t)((nc * 4 + kc) * 64 + lane) * 8);
            acc = __builtin_amdgcn_mfma_f32_16x16x32_bf16(a[kc], b, acc, 0, 0, 0);
        }
        ushort* hp = H + (size_t)(r0 + quad * 4) * 128 + nc * 16 + lo;
        #pragma unroll
        for (int r = 0; r < 4; r++)
            hp[(size_t)r * 128] = (ushort)f2bf(acc[r]);
    }
}

// ---------------------------------------------------------------------------
// Fused aggregation (CSR, bf16 gather) + self-loop + bias + residual + LN.
// One wave per node; lane owns dims {2*lane, 2*lane+1}. Gather loop: ILP=8
// with clamped tail (OOB -> re-read epack[e0], weight 0) — no scalar tail.
template<int SHIFT, bool RESID_BF, bool OUT_BF>
__global__ __launch_bounds__(256) void agg_ln(const int* __restrict__ row_ptr,
                                              const int2* __restrict__ epack,
                                              const float* __restrict__ dis,
                                              const uint* __restrict__ hb,
                                              const int* __restrict__ nid,
                                              const void* __restrict__ resid,
                                              const float* __restrict__ bias,
                                              const float* __restrict__ gamma,
                                              const float* __restrict__ beta,
                                              void* __restrict__ out, int n) {
    int i = (blockIdx.x * 256 + threadIdx.x) >> 6;
    int lane = threadIdx.x & 63;
    if (i >= n) return;
    int hri = nid ? nid[i] : i;
    float dl = dis[i];
    uint ps = hb[(size_t)hri * 64 + lane];
    float sx[4] = {dl * bf_lo(ps), 0.f, 0.f, 0.f};   // self-loop; *dl later -> dl^2
    float sy[4] = {dl * bf_hi(ps), 0.f, 0.f, 0.f};
    int e0 = row_ptr[i], e1 = row_ptr[i + 1];
    for (int j = e0; j < e1; j += 8) {
        int2 er[8];
        #pragma unroll
        for (int k = 0; k < 8; k++) {
            int idx = (j + k < e1) ? j + k : e0;     // clamp to a valid record
            er[k] = epack[idx];
        }
        uint qv[8];
        #pragma unroll
        for (int k = 0; k < 8; k++)
            qv[k] = hb[(size_t)(((uint)er[k].x >> SHIFT) & 0xffffu) * 64 + lane];
        #pragma unroll
        for (int k = 0; k < 8; k++) {
            float w = (j + k < e1) ? __int_as_float(er[k].y) : 0.f;
            sx[k & 3] += w * bf_lo(qv[k]);
            sy[k & 3] += w * bf_hi(qv[k]);
        }
    }
    float acc0 = (sx[0] + sx[1]) + (sx[2] + sx[3]);
    float acc1 = (sy[0] + sy[1]) + (sy[2] + sy[3]);
    float2 xr;
    if (RESID_BF) {
        uint pr = ((const uint*)resid)[(size_t)hri * 64 + lane];
        xr = make_float2(bf_lo(pr), bf_hi(pr));
    } else {
        xr = ((const float2*)resid)[(size_t)hri * 64 + lane];
    }
    float2 bi = ((const float2*)bias)[lane];
    float v0 = xr.x + dl * acc0 + bi.x;
    float v1 = xr.y + dl * acc1 + bi.y;
    float s1 = v0 + v1, s2 = v0 * v0 + v1 * v1;
    #pragma unroll
    for (int o = 32; o > 0; o >>= 1) {
        s1 += __shfl_xor(s1, o, 64);
        s2 += __shfl_xor(s2, o, 64);
    }
    float mu   = s1 * (1.0f / DIM);
    float var  = s2 * (1.0f / DIM) - mu * mu;
    float rstd = rsqrtf(var + LN_EPS);
    float2 ga = ((const float2*)gamma)[lane];
    float2 be = ((const float2*)beta)[lane];
    float o0 = (v0 - mu) * rstd * ga.x + be.x;
    float o1 = (v1 - mu) * rstd * ga.y + be.y;
    if (OUT_BF) {
        ((uint*)out)[(size_t)i * 64 + lane] = f2bf(o0) | (f2bf(o1) << 16);
    } else {
        ((float2*)out)[(size_t)i * 64 + lane] = make_float2(o0, o1);
    }
}

// ---------------------------------------------------------------------------
extern "C" void kernel_launch(void* const* d_in, const int* in_sizes, int n_in,
                              void* d_out, int out_size, void* d_ws, size_t ws_size,
                              hipStream_t stream) {
    const int*   node_ids = (const int*)  d_in[0];
    const int*   ei       = (const int*)  d_in[1];   // [2, E]
    const float* ew       = (const float*)d_in[2];
    const float* emb      = (const float*)d_in[3];   // [VOCAB, 128]
    const float* W1       = (const float*)d_in[4];
    const float* b1       = (const float*)d_in[5];
    const float* W2       = (const float*)d_in[6];
    const float* b2       = (const float*)d_in[7];
    const float* g1       = (const float*)d_in[8];
    const float* be1      = (const float*)d_in[9];
    const float* g2       = (const float*)d_in[10];
    const float* be2      = (const float*)d_in[11];
    float* out = (float*)d_out;

    // workspace carve-out (256B aligned), total ~34 MB
    char* p = (char*)d_ws;
    auto alloc = [&](size_t bytes) {
        char* r = p;
        p += (bytes + 255) & ~(size_t)255;
        return r;
    };
    uint*   h2b     = (uint*)  alloc((size_t)N_NODES * 64 * 4);  // 12.8 MB bf16x2
    uint*   x1b     = (uint*)  alloc((size_t)N_NODES * 64 * 4);  // 12.8 MB bf16x2
    uint*   hembB   = (uint*)  alloc((size_t)VOCAB * 64 * 4);    // 128 KB bf16x2
    ushort* Wp      = (ushort*)alloc((size_t)128 * 128 * 2);     // 32 KB B-frags
    ull*    pack    = (ull*)   alloc((size_t)N_NODES * 8);
    float*  disv    = (float*) alloc((size_t)N_NODES * 4);
    int*    row_ptr = (int*)   alloc((size_t)(N_NODES + 1) * 4);
    int*    rank    = (int*)   alloc((size_t)N_EDGES * 4);
    int*    bsum    = (int*)   alloc(64 * 4);
    int*    bofs    = (int*)   alloc(64 * 4);
    int2*   epack   = (int2*)  alloc((size_t)N_EDGES * 8);       // 4.8 MB

    int nb = (N_NODES + 1023) / 1024;  // 49

    // --- CSR + normalization build (shared by both layers) ---
    hipMemsetAsync(pack, 0, (size_t)N_NODES * 8, stream);
    deg_rank_kernel<<<(N_EDGES / 4 + 255) / 256, 256, 0, stream>>>(ei, ew, pack, rank, N_EDGES);
    scan_a<<<nb, 1024, 0, stream>>>(pack, disv, row_ptr, bsum, N_NODES);
    scan_b<<<1, 64, 0, stream>>>(bsum, bofs, nb);
    scan_c<<<nb, 1024, 0, stream>>>(row_ptr, bofs, N_NODES, N_EDGES);
    scatter_kernel<<<(N_EDGES + 255) / 256, 256, 0, stream>>>(ei, ew, disv, node_ids,
                                                              row_ptr, rank, epack, N_EDGES);
    prepack_w<<<64, 256, 0, stream>>>(W2, Wp);

    // --- Layer 1: x@W1 == (emb@W1)[node_ids]  -> only a 512-row matmul ---
    matmul128<<<(VOCAB + 63) / 64, 256, 0, stream>>>(emb, W1, hembB, VOCAB);
    agg_ln<16, false, true><<<(N_NODES + 3) / 4, 256, 0, stream>>>(
        row_ptr, epack, disv, hembB, node_ids, emb, b1, g1, be1, x1b, N_NODES);

    // --- Layer 2: MFMA bf16 matmul, then fused agg+LN -> d_out ---
    mm2_mfma<<<(N_NODES / 16 + 3) / 4, 256, 0, stream>>>(x1b, Wp, (ushort*)h2b, N_NODES);
    agg_ln<0, true, false><<<(N_NODES + 3) / 4, 256, 0, stream>>>(
        row_ptr, epack, disv, h2b, nullptr, x1b, b2, g2, be2, out, N_NODES);
}

// Round 7
// 226.362 us; speedup vs baseline: 1.5783x; 1.0701x over previous
//
#include <hip/hip_runtime.h>

#define N_NODES 50000
#define N_EDGES 600000
#define DIM     128
#define VOCAB   512
#define LN_EPS  1e-5f
#define FIXS    16777216.0f   // 2^24 fixed-point scale for weight sums

typedef unsigned int uint;
typedef unsigned long long ull;
typedef unsigned short ushort;
typedef __attribute__((ext_vector_type(8))) short s8v;   // 8 bf16 (4 VGPRs)
typedef __attribute__((ext_vector_type(4))) float f4v;   // 4 fp32 acc
typedef __attribute__((ext_vector_type(4))) int   i4v;   // nontemporal-friendly
typedef __attribute__((ext_vector_type(4))) uint  u4v;
typedef __attribute__((ext_vector_type(2))) int   i2v;
typedef __attribute__((ext_vector_type(4))) float fv4;
typedef __attribute__((ext_vector_type(2))) float f2v;

// round-to-nearest-even fp32 -> bf16 (as uint16 in low bits)
__device__ __forceinline__ uint f2bf(float f) {
    uint u = __float_as_uint(f);
    return (u + 0x7fffu + ((u >> 16) & 1u)) >> 16;
}
__device__ __forceinline__ float bf_lo(uint p) { return __uint_as_float(p << 16); }
__device__ __forceinline__ float bf_hi(uint p) { return __uint_as_float(p & 0xffff0000u); }

// ---------------------------------------------------------------------------
// K1: single 64-bit atomic per edge accumulates {count, fixed-point weight sum}
// per destination; returned old count = rank of this edge within its bucket.
// ILP=8: eight independent atomic chains per thread (E % 8 == 0).
__global__ void deg_rank_kernel(const int* __restrict__ ei, const float* __restrict__ ew,
                                ull* pack, ushort* __restrict__ rank, int E) {
    int e0 = (blockIdx.x * blockDim.x + threadIdx.x) * 8;
    if (e0 >= E) return;
    i4v c0 = __builtin_nontemporal_load((const i4v*)(ei + E + e0));
    i4v c1 = __builtin_nontemporal_load((const i4v*)(ei + E + e0 + 4));
    fv4 w0 = __builtin_nontemporal_load((const fv4*)(ew + e0));
    fv4 w1 = __builtin_nontemporal_load((const fv4*)(ew + e0 + 4));
    int   c[8] = {c0.x, c0.y, c0.z, c0.w, c1.x, c1.y, c1.z, c1.w};
    float w[8] = {w0.x, w0.y, w0.z, w0.w, w1.x, w1.y, w1.z, w1.w};
    ull r[8];
    #pragma unroll
    for (int k = 0; k < 8; k++) {
        ull a = (1ull << 32) | (ull)(uint)__float2int_rn(w[k] * FIXS);
        r[k] = atomicAdd(&pack[c[k]], a);       // 8 independent chains in flight
    }
    u4v o;
    o.x = (uint)(r[0] >> 32) | ((uint)(r[1] >> 32) << 16);
    o.y = (uint)(r[2] >> 32) | ((uint)(r[3] >> 32) << 16);
    o.z = (uint)(r[4] >> 32) | ((uint)(r[5] >> 32) << 16);
    o.w = (uint)(r[6] >> 32) | ((uint)(r[7] >> 32) << 16);
    __builtin_nontemporal_store(o, (u4v*)(rank + e0));
}

// K2a: per-block exclusive scan of counts (chunk of 1024) + dis = rsqrt(1+deg)
__global__ void scan_a(const ull* __restrict__ pack,
                       float* dis, int* row_ptr, int* bsum, int n) {
    __shared__ int sd[1024];
    int t = threadIdx.x;
    int i = blockIdx.x * 1024 + t;
    int v = 0;
    if (i < n) {
        ull pv = pack[i];
        v = (int)(pv >> 32);
        dis[i] = rsqrtf(1.0f + (float)(uint)(pv & 0xffffffffu) * (1.0f / FIXS));
    }
    sd[t] = v;
    __syncthreads();
    for (int off = 1; off < 1024; off <<= 1) {
        int add = (t >= off) ? sd[t - off] : 0;
        __syncthreads();
        sd[t] += add;
        __syncthreads();
    }
    if (i < n) row_ptr[i] = sd[t] - v;     // block-local exclusive
    if (t == 1023) bsum[blockIdx.x] = sd[t];
}

// K2c (scan_b fused in): each block sums bsum[0..blockIdx) with one wave
// butterfly, then adds its offset to row_ptr.
__global__ void scan_c(int* row_ptr, const int* __restrict__ bsum,
                       int n, int E, int nb) {
    __shared__ int ofs_s;
    int t = threadIdx.x;
    if (t < 64) {
        int v = (t < nb && t < (int)blockIdx.x) ? bsum[t] : 0;
        #pragma unroll
        for (int o = 32; o > 0; o >>= 1) v += __shfl_xor(v, o, 64);
        if (t == 0) ofs_s = v;
    }
    __syncthreads();
    int i = blockIdx.x * 1024 + t;
    if (i < n) row_ptr[i] += ofs_s;
    if (i == 0) row_ptr[n] = E;
}

// K3: atomic-free CSR scatter. pos = row_ptr[dst] + rank[e].
// Record: bits 0-15 = src (layer-2 row), bits 16-24 = node_ids[src] (layer-1
// row). w' = dis[src]*ew; dis[dst] is wave-uniform in agg, applied there.
__global__ void scatter_kernel(const int* __restrict__ ei, const float* __restrict__ ew,
                               const float* __restrict__ dis, const int* __restrict__ nid,
                               const int* __restrict__ row_ptr, const ushort* __restrict__ rank,
                               int2* __restrict__ epack, int E) {
    int e = blockIdx.x * blockDim.x + threadIdx.x;
    if (e < E) {
        int s = ei[e];
        int c = ei[E + e];
        int pos = row_ptr[c] + (int)rank[e];
        uint ids = (uint)s | ((uint)nid[s] << 16);
        float wp = dis[s] * ew[e];
        i2v rec = {(int)ids, __float_as_int(wp)};
        __builtin_nontemporal_store(rec, (i2v*)(epack + pos));
    }
}

// ---------------------------------------------------------------------------
// K4: layer-1 matmul (M=512, fp32) fused with W2 B-fragment prepack.
// blocks 0..7: Hb = X @ W1 -> bf16x2.  blocks 8..71: pack W2 into MFMA
// B-frag order Wp[((nc*4+kc)*64+lane)*8+j] = bf16(W2[k][n]),
// k=kc*32+(lane>>4)*8+j, n=nc*16+(lane&15).
__global__ __launch_bounds__(256) void mm1_prepack(const float* __restrict__ X,
                                                   const float* __restrict__ W,
                                                   uint* __restrict__ Hb, int M,
                                                   const float* __restrict__ W2,
                                                   ushort* __restrict__ Wp) {
    __shared__ float Wt[32 * 128];
    __shared__ float Xt[64 * 36];
    int tid = threadIdx.x;
    int nmm = (M + 63) / 64;
    if ((int)blockIdx.x >= nmm) {          // prepack path
        int o = (blockIdx.x - nmm) * 256 + tid;      // 0..16383
        int j = o & 7, lane = (o >> 3) & 63, chunk = o >> 9;
        int kc = chunk & 3, nc = chunk >> 2;
        int k = kc * 32 + (lane >> 4) * 8 + j;
        int n = nc * 16 + (lane & 15);
        Wp[o] = (ushort)f2bf(W2[k * 128 + n]);
        return;
    }
    int tx = tid & 31, ty = tid >> 5;
    int r0 = blockIdx.x * 64;
    float acc[8][4];
    #pragma unroll
    for (int j = 0; j < 8; j++)
        #pragma unroll
        for (int c = 0; c < 4; c++) acc[j][c] = 0.f;

    for (int kb = 0; kb < 128; kb += 32) {
        __syncthreads();
        #pragma unroll
        for (int q = 0; q < 4; q++) {
            int f = q * 256 + tid;
            ((float4*)Wt)[f] = *(const float4*)(W + kb * 128 + f * 4);
        }
        #pragma unroll
        for (int q = 0; q < 2; q++) {
            int f = q * 256 + tid;
            int row = f >> 3, cs = f & 7;
            int gr = r0 + row;
            float4 xv = make_float4(0.f, 0.f, 0.f, 0.f);
            if (gr < M) xv = *(const float4*)(X + (size_t)gr * 128 + kb + cs * 4);
            *(float4*)(Xt + row * 36 + cs * 4) = xv;
        }
        __syncthreads();
        #pragma unroll
        for (int k = 0; k < 32; k += 4) {
            float wv[4][4];
            #pragma unroll
            for (int kk = 0; kk < 4; kk++) {
                float4 t4 = *(const float4*)(Wt + (k + kk) * 128 + tx * 4);
                wv[kk][0] = t4.x; wv[kk][1] = t4.y; wv[kk][2] = t4.z; wv[kk][3] = t4.w;
            }
            #pragma unroll
            for (int j = 0; j < 8; j++) {
                float4 xv = *(const float4*)(Xt + (ty * 8 + j) * 36 + k);
                float xs[4] = {xv.x, xv.y, xv.z, xv.w};
                #pragma unroll
                for (int kk = 0; kk < 4; kk++)
                    #pragma unroll
                    for (int c = 0; c < 4; c++)
                        acc[j][c] = fmaf(xs[kk], wv[kk][c], acc[j][c]);
            }
        }
    }
    #pragma unroll
    for (int j = 0; j < 8; j++) {
        int gr = r0 + ty * 8 + j;
        if (gr < M) {
            uint p0 = f2bf(acc[j][0]) | (f2bf(acc[j][1]) << 16);
            uint p1 = f2bf(acc[j][2]) | (f2bf(acc[j][3]) << 16);
            ((uint2*)Hb)[(size_t)gr * 32 + tx] = make_uint2(p0, p1);
        }
    }
}

// ---------------------------------------------------------------------------
// K5: MFMA bf16 matmul (layer 2): H[M x 128 bf16] = Xb[M x 128 bf16] @ W2.
// One wave per 16 rows; 8 n-chunks x 4 k-chunks of mfma_f32_16x16x32_bf16.
// C/D layout: row=(lane>>4)*4+reg, col=lane&15 [m89/m91-verified].
__global__ __launch_bounds__(256) void mm2_mfma(const uint* __restrict__ Xb,
                                                const ushort* __restrict__ Wp,
                                                ushort* __restrict__ H, int M) {
    int wid = (blockIdx.x * 256 + threadIdx.x) >> 6;
    int lane = threadIdx.x & 63;
    int r0 = wid * 16;
    if (r0 >= M) return;                    // M % 16 == 0: no partial tiles
    int quad = lane >> 4, lo = lane & 15;
    const uint* xrow = Xb + (size_t)(r0 + lo) * 64 + quad * 4;
    s8v a[4];
    #pragma unroll
    for (int kc = 0; kc < 4; kc++) a[kc] = *(const s8v*)(xrow + kc * 16);
    #pragma unroll
    for (int nc = 0; nc < 8; nc++) {
        f4v acc = {0.f, 0.f, 0.f, 0.f};
        #pragma unroll
        for (int kc = 0; kc < 4; kc++) {
            s8v b = *(const s8v*)(Wp + (size_t)((nc * 4 + kc) * 64 + lane) * 8);
            acc = __builtin_amdgcn_mfma_f32_16x16x32_bf16(a[kc], b, acc, 0, 0, 0);
        }
        ushort* hp = H + (size_t)(r0 + quad * 4) * 128 + nc * 16 + lo;
        #pragma unroll
        for (int r = 0; r < 4; r++)
            hp[(size_t)r * 128] = (ushort)f2bf(acc[r]);
    }
}

// ---------------------------------------------------------------------------
// Fused aggregation (CSR, bf16 gather) + self-loop + bias + residual + LN.
// One wave per node; lane owns dims {2*lane, 2*lane+1}. Gather loop: ILP=8
// with clamped tail. epack/resid streamed nontemporally to keep the gather
// table (hb) resident in L2; out stores nontemporal.
template<int SHIFT, bool RESID_BF, bool OUT_BF>
__global__ __launch_bounds__(256) void agg_ln(const int* __restrict__ row_ptr,
                                              const int2* __restrict__ epack,
                                              const float* __restrict__ dis,
                                              const uint* __restrict__ hb,
                                              const int* __restrict__ nid,
                                              const void* __restrict__ resid,
                                              const float* __restrict__ bias,
                                              const float* __restrict__ gamma,
                                              const float* __restrict__ beta,
                                              void* __restrict__ out, int n) {
    int i = (blockIdx.x * 256 + threadIdx.x) >> 6;
    int lane = threadIdx.x & 63;
    if (i >= n) return;
    int iw = __builtin_amdgcn_readfirstlane(i);      // wave-uniform -> s_load
    int hri = nid ? nid[iw] : iw;
    float dl = dis[iw];
    uint ps = hb[(size_t)hri * 64 + lane];
    float sx[4] = {dl * bf_lo(ps), 0.f, 0.f, 0.f};   // self-loop; *dl later -> dl^2
    float sy[4] = {dl * bf_hi(ps), 0.f, 0.f, 0.f};
    int e0 = row_ptr[iw], e1 = row_ptr[iw + 1];
    for (int j = e0; j < e1; j += 8) {
        i2v er[8];
        #pragma unroll
        for (int k = 0; k < 8; k++) {
            int idx = (j + k < e1) ? j + k : e0;     // clamp to a valid record
            er[k] = __builtin_nontemporal_load((const i2v*)(epack + idx));
        }
        uint qv[8];
        #pragma unroll
        for (int k = 0; k < 8; k++)
            qv[k] = hb[(size_t)(((uint)er[k].x >> SHIFT) & 0xffffu) * 64 + lane];
        #pragma unroll
        for (int k = 0; k < 8; k++) {
            float w = (j + k < e1) ? __int_as_float(er[k].y) : 0.f;
            sx[k & 3] += w * bf_lo(qv[k]);
            sy[k & 3] += w * bf_hi(qv[k]);
        }
    }
    float acc0 = (sx[0] + sx[1]) + (sx[2] + sx[3]);
    float acc1 = (sy[0] + sy[1]) + (sy[2] + sy[3]);
    float2 xr;
    if (RESID_BF) {
        uint pr = __builtin_nontemporal_load((const uint*)resid + (size_t)hri * 64 + lane);
        xr = make_float2(bf_lo(pr), bf_hi(pr));
    } else {
        xr = ((const float2*)resid)[(size_t)hri * 64 + lane];
    }
    float2 bi = ((const float2*)bias)[lane];
    float v0 = xr.x + dl * acc0 + bi.x;
    float v1 = xr.y + dl * acc1 + bi.y;
    float s1 = v0 + v1, s2 = v0 * v0 + v1 * v1;
    #pragma unroll
    for (int o = 32; o > 0; o >>= 1) {
        s1 += __shfl_xor(s1, o, 64);
        s2 += __shfl_xor(s2, o, 64);
    }
    float mu   = s1 * (1.0f / DIM);
    float var  = s2 * (1.0f / DIM) - mu * mu;
    float rstd = rsqrtf(var + LN_EPS);
    float2 ga = ((const float2*)gamma)[lane];
    float2 be = ((const float2*)beta)[lane];
    float o0 = (v0 - mu) * rstd * ga.x + be.x;
    float o1 = (v1 - mu) * rstd * ga.y + be.y;
    if (OUT_BF) {
        __builtin_nontemporal_store(f2bf(o0) | (f2bf(o1) << 16),
                                    (uint*)out + (size_t)i * 64 + lane);
    } else {
        f2v ov = {o0, o1};
        __builtin_nontemporal_store(ov, (f2v*)((float2*)out + (size_t)i * 64 + lane));
    }
}

// ---------------------------------------------------------------------------
extern "C" void kernel_launch(void* const* d_in, const int* in_sizes, int n_in,
                              void* d_out, int out_size, void* d_ws, size_t ws_size,
                              hipStream_t stream) {
    const int*   node_ids = (const int*)  d_in[0];
    const int*   ei       = (const int*)  d_in[1];   // [2, E]
    const float* ew       = (const float*)d_in[2];
    const float* emb      = (const float*)d_in[3];   // [VOCAB, 128]
    const float* W1       = (const float*)d_in[4];
    const float* b1       = (const float*)d_in[5];
    const float* W2       = (const float*)d_in[6];
    const float* b2       = (const float*)d_in[7];
    const float* g1       = (const float*)d_in[8];
    const float* be1      = (const float*)d_in[9];
    const float* g2       = (const float*)d_in[10];
    const float* be2      = (const float*)d_in[11];
    float* out = (float*)d_out;

    // workspace carve-out (256B aligned), total ~33 MB
    char* p = (char*)d_ws;
    auto alloc = [&](size_t bytes) {
        char* r = p;
        p += (bytes + 255) & ~(size_t)255;
        return r;
    };
    uint*   h2b     = (uint*)  alloc((size_t)N_NODES * 64 * 4);  // 12.8 MB bf16x2
    uint*   x1b     = (uint*)  alloc((size_t)N_NODES * 64 * 4);  // 12.8 MB bf16x2
    uint*   hembB   = (uint*)  alloc((size_t)VOCAB * 64 * 4);    // 128 KB bf16x2
    ushort* Wp      = (ushort*)alloc((size_t)128 * 128 * 2);     // 32 KB B-frags
    ull*    pack    = (ull*)   alloc((size_t)N_NODES * 8);
    float*  disv    = (float*) alloc((size_t)N_NODES * 4);
    int*    row_ptr = (int*)   alloc((size_t)(N_NODES + 1) * 4);
    ushort* rank    = (ushort*)alloc((size_t)N_EDGES * 2);       // 1.2 MB
    int*    bsum    = (int*)   alloc(64 * 4);
    int2*   epack   = (int2*)  alloc((size_t)N_EDGES * 8);       // 4.8 MB

    int nb = (N_NODES + 1023) / 1024;  // 49

    // --- CSR + normalization build (shared by both layers) ---
    (void)hipMemsetAsync(pack, 0, (size_t)N_NODES * 8, stream);
    deg_rank_kernel<<<(N_EDGES / 8 + 255) / 256, 256, 0, stream>>>(ei, ew, pack, rank, N_EDGES);
    scan_a<<<nb, 1024, 0, stream>>>(pack, disv, row_ptr, bsum, N_NODES);
    scan_c<<<nb, 1024, 0, stream>>>(row_ptr, bsum, N_NODES, N_EDGES, nb);
    scatter_kernel<<<(N_EDGES + 255) / 256, 256, 0, stream>>>(ei, ew, disv, node_ids,
                                                              row_ptr, rank, epack, N_EDGES);

    // --- Layer 1 matmul (512 rows) + W2 prepack in one launch ---
    mm1_prepack<<<(VOCAB + 63) / 64 + 64, 256, 0, stream>>>(emb, W1, hembB, VOCAB, W2, Wp);
    agg_ln<16, false, true><<<(N_NODES + 3) / 4, 256, 0, stream>>>(
        row_ptr, epack, disv, hembB, node_ids, emb, b1, g1, be1, x1b, N_NODES);

    // --- Layer 2: MFMA bf16 matmul, then fused agg+LN -> d_out ---
    mm2_mfma<<<(N_NODES / 16 + 3) / 4, 256, 0, stream>>>(x1b, Wp, (ushort*)h2b, N_NODES);
    agg_ln<0, true, false><<<(N_NODES + 3) / 4, 256, 0, stream>>>(
        row_ptr, epack, disv, h2b, nullptr, x1b, b2, g2, be2, out, N_NODES);
}

// Round 8
// 216.763 us; speedup vs baseline: 1.6482x; 1.0443x over previous
//
#include <hip/hip_runtime.h>

#define N_NODES 50000
#define N_EDGES 600000
#define DIM     128
#define VOCAB   512
#define LN_EPS  1e-5f
#define FIXS    16777216.0f   // 2^24 fixed-point scale for weight sums

typedef unsigned int uint;
typedef unsigned long long ull;
typedef unsigned short ushort;
typedef unsigned char uchar;
typedef __attribute__((ext_vector_type(8))) short s8v;   // 8 bf16 (4 VGPRs)
typedef __attribute__((ext_vector_type(4))) float f4v;   // 4 fp32 acc
typedef __attribute__((ext_vector_type(4))) int   i4v;   // nontemporal-friendly
typedef __attribute__((ext_vector_type(4))) uint  u4v;
typedef __attribute__((ext_vector_type(2))) int   i2v;
typedef __attribute__((ext_vector_type(4))) float fv4;
typedef __attribute__((ext_vector_type(2))) float f2v;

// round-to-nearest-even fp32 -> bf16 (as uint16 in low bits)
__device__ __forceinline__ uint f2bf(float f) {
    uint u = __float_as_uint(f);
    return (u + 0x7fffu + ((u >> 16) & 1u)) >> 16;
}
__device__ __forceinline__ float bf_lo(uint p) { return __uint_as_float(p << 16); }
__device__ __forceinline__ float bf_hi(uint p) { return __uint_as_float(p & 0xffff0000u); }

// fp8 e4m3: HW pack/unpack (encode+decode are the same HW format -> self-consistent)
__device__ __forceinline__ uchar f2fp8(float v) {
    return (uchar)(__builtin_amdgcn_cvt_pk_fp8_f32(v, v, 0, false) & 0xff);
}
__device__ __forceinline__ f2v fp8x2_to_f2(uint packed2) {
    return __builtin_amdgcn_cvt_pk_f32_fp8((int)packed2, false);
}

// ---------------------------------------------------------------------------
// K1 (fused): blocks [0, nbDeg): per-edge 64-bit atomic {count, fixsum} -> rank.
// blocks [nbDeg, nbDeg+8): layer-1 matmul Hb = emb @ W1 (M=512 fp32 -> bf16x2).
// blocks [nbDeg+8, nbDeg+72): pack W2 into MFMA B-frag order (bf16).
__global__ __launch_bounds__(256) void deg_mm1_kernel(
        const int* __restrict__ ei, const float* __restrict__ ew,
        ull* pack, ushort* __restrict__ rank, int E,
        const float* __restrict__ X, const float* __restrict__ W,
        uint* __restrict__ Hb, int M,
        const float* __restrict__ W2, ushort* __restrict__ Wp) {
    __shared__ float Wt[32 * 128];
    __shared__ float Xt[64 * 36];
    int tid = threadIdx.x;
    int nbDeg = (E / 8 + 255) / 256;
    int nmm = (M + 63) / 64;
    if ((int)blockIdx.x < nbDeg) {
        // ---- deg/rank path: 8 independent atomic chains per thread ----
        int e0 = (blockIdx.x * 256 + tid) * 8;
        if (e0 >= E) return;
        i4v c0 = __builtin_nontemporal_load((const i4v*)(ei + E + e0));
        i4v c1 = __builtin_nontemporal_load((const i4v*)(ei + E + e0 + 4));
        fv4 w0 = __builtin_nontemporal_load((const fv4*)(ew + e0));
        fv4 w1 = __builtin_nontemporal_load((const fv4*)(ew + e0 + 4));
        int   c[8] = {c0.x, c0.y, c0.z, c0.w, c1.x, c1.y, c1.z, c1.w};
        float w[8] = {w0.x, w0.y, w0.z, w0.w, w1.x, w1.y, w1.z, w1.w};
        ull r[8];
        #pragma unroll
        for (int k = 0; k < 8; k++) {
            ull a = (1ull << 32) | (ull)(uint)__float2int_rn(w[k] * FIXS);
            r[k] = atomicAdd(&pack[c[k]], a);
        }
        u4v o;
        o.x = (uint)(r[0] >> 32) | ((uint)(r[1] >> 32) << 16);
        o.y = (uint)(r[2] >> 32) | ((uint)(r[3] >> 32) << 16);
        o.z = (uint)(r[4] >> 32) | ((uint)(r[5] >> 32) << 16);
        o.w = (uint)(r[6] >> 32) | ((uint)(r[7] >> 32) << 16);
        __builtin_nontemporal_store(o, (u4v*)(rank + e0));
        return;
    }
    if ((int)blockIdx.x >= nbDeg + nmm) {
        // ---- W2 prepack path ----
        int o = (blockIdx.x - nbDeg - nmm) * 256 + tid;    // 0..16383
        int j = o & 7, lane = (o >> 3) & 63, chunk = o >> 9;
        int kc = chunk & 3, nc = chunk >> 2;
        int k = kc * 32 + (lane >> 4) * 8 + j;
        int n = nc * 16 + (lane & 15);
        Wp[o] = (ushort)f2bf(W2[k * 128 + n]);
        return;
    }
    // ---- layer-1 matmul path ----
    int bx = blockIdx.x - nbDeg;
    int tx = tid & 31, ty = tid >> 5;
    int r0 = bx * 64;
    float acc[8][4];
    #pragma unroll
    for (int j = 0; j < 8; j++)
        #pragma unroll
        for (int c = 0; c < 4; c++) acc[j][c] = 0.f;

    for (int kb = 0; kb < 128; kb += 32) {
        __syncthreads();
        #pragma unroll
        for (int q = 0; q < 4; q++) {
            int f = q * 256 + tid;
            ((float4*)Wt)[f] = *(const float4*)(W + kb * 128 + f * 4);
        }
        #pragma unroll
        for (int q = 0; q < 2; q++) {
            int f = q * 256 + tid;
            int row = f >> 3, cs = f & 7;
            int gr = r0 + row;
            float4 xv = make_float4(0.f, 0.f, 0.f, 0.f);
            if (gr < M) xv = *(const float4*)(X + (size_t)gr * 128 + kb + cs * 4);
            *(float4*)(Xt + row * 36 + cs * 4) = xv;
        }
        __syncthreads();
        #pragma unroll
        for (int k = 0; k < 32; k += 4) {
            float wv[4][4];
            #pragma unroll
            for (int kk = 0; kk < 4; kk++) {
                float4 t4 = *(const float4*)(Wt + (k + kk) * 128 + tx * 4);
                wv[kk][0] = t4.x; wv[kk][1] = t4.y; wv[kk][2] = t4.z; wv[kk][3] = t4.w;
            }
            #pragma unroll
            for (int j = 0; j < 8; j++) {
                float4 xv = *(const float4*)(Xt + (ty * 8 + j) * 36 + k);
                float xs[4] = {xv.x, xv.y, xv.z, xv.w};
                #pragma unroll
                for (int kk = 0; kk < 4; kk++)
                    #pragma unroll
                    for (int c = 0; c < 4; c++)
                        acc[j][c] = fmaf(xs[kk], wv[kk][c], acc[j][c]);
            }
        }
    }
    #pragma unroll
    for (int j = 0; j < 8; j++) {
        int gr = r0 + ty * 8 + j;
        if (gr < M) {
            uint p0 = f2bf(acc[j][0]) | (f2bf(acc[j][1]) << 16);
            uint p1 = f2bf(acc[j][2]) | (f2bf(acc[j][3]) << 16);
            ((uint2*)Hb)[(size_t)gr * 32 + tx] = make_uint2(p0, p1);
        }
    }
}

// K2a: per-block exclusive scan of counts (chunk of 1024) + dis = rsqrt(1+deg)
__global__ void scan_a(const ull* __restrict__ pack,
                       float* dis, int* row_ptr, int* bsum, int n) {
    __shared__ int sd[1024];
    int t = threadIdx.x;
    int i = blockIdx.x * 1024 + t;
    int v = 0;
    if (i < n) {
        ull pv = pack[i];
        v = (int)(pv >> 32);
        dis[i] = rsqrtf(1.0f + (float)(uint)(pv & 0xffffffffu) * (1.0f / FIXS));
    }
    sd[t] = v;
    __syncthreads();
    for (int off = 1; off < 1024; off <<= 1) {
        int add = (t >= off) ? sd[t - off] : 0;
        __syncthreads();
        sd[t] += add;
        __syncthreads();
    }
    if (i < n) row_ptr[i] = sd[t] - v;     // block-local exclusive
    if (t == 1023) bsum[blockIdx.x] = sd[t];
}

// K2c: each block sums bsum[0..blockIdx) with a wave butterfly, adds offset.
__global__ void scan_c(int* row_ptr, const int* __restrict__ bsum,
                       int n, int E, int nb) {
    __shared__ int ofs_s;
    int t = threadIdx.x;
    if (t < 64) {
        int v = (t < nb && t < (int)blockIdx.x) ? bsum[t] : 0;
        #pragma unroll
        for (int o = 32; o > 0; o >>= 1) v += __shfl_xor(v, o, 64);
        if (t == 0) ofs_s = v;
    }
    __syncthreads();
    int i = blockIdx.x * 1024 + t;
    if (i < n) row_ptr[i] += ofs_s;
    if (i == 0) row_ptr[n] = E;
}

// K3: atomic-free CSR scatter. pos = row_ptr[dst] + rank[e].
__global__ void scatter_kernel(const int* __restrict__ ei, const float* __restrict__ ew,
                               const float* __restrict__ dis, const int* __restrict__ nid,
                               const int* __restrict__ row_ptr, const ushort* __restrict__ rank,
                               int2* __restrict__ epack, int E) {
    int e = blockIdx.x * blockDim.x + threadIdx.x;
    if (e < E) {
        int s = ei[e];
        int c = ei[E + e];
        int pos = row_ptr[c] + (int)rank[e];
        uint ids = (uint)s | ((uint)nid[s] << 16);
        float wp = dis[s] * ew[e];
        i2v rec = {(int)ids, __float_as_int(wp)};
        __builtin_nontemporal_store(rec, (i2v*)(epack + pos));
    }
}

// ---------------------------------------------------------------------------
// K5: MFMA bf16 matmul (layer 2): H8[M x 128 fp8 e4m3] = Xb[bf16] @ W2.
// One wave per 16 rows; C/D layout row=(lane>>4)*4+reg, col=lane&15.
__global__ __launch_bounds__(256) void mm2_mfma(const uint* __restrict__ Xb,
                                                const ushort* __restrict__ Wp,
                                                uchar* __restrict__ H8, int M) {
    int wid = (blockIdx.x * 256 + threadIdx.x) >> 6;
    int lane = threadIdx.x & 63;
    int r0 = wid * 16;
    if (r0 >= M) return;                    // M % 16 == 0: no partial tiles
    int quad = lane >> 4, lo = lane & 15;
    const uint* xrow = Xb + (size_t)(r0 + lo) * 64 + quad * 4;
    s8v a[4];
    #pragma unroll
    for (int kc = 0; kc < 4; kc++) a[kc] = *(const s8v*)(xrow + kc * 16);
    #pragma unroll
    for (int nc = 0; nc < 8; nc++) {
        f4v acc = {0.f, 0.f, 0.f, 0.f};
        #pragma unroll
        for (int kc = 0; kc < 4; kc++) {
            s8v b = *(const s8v*)(Wp + (size_t)((nc * 4 + kc) * 64 + lane) * 8);
            acc = __builtin_amdgcn_mfma_f32_16x16x32_bf16(a[kc], b, acc, 0, 0, 0);
        }
        uchar* hp = H8 + (size_t)(r0 + quad * 4) * 128 + nc * 16 + lo;
        #pragma unroll
        for (int r = 0; r < 4; r++)
            hp[(size_t)r * 128] = f2fp8(acc[r]);
    }
}

// ---------------------------------------------------------------------------
// Fused aggregation (CSR) + self-loop + bias + residual + LayerNorm.
// One wave per node; lane owns dims {2*lane, 2*lane+1}. Gather loop: ILP=8
// with clamped tail. GF8: gather table is fp8 e4m3 (2 B/lane) else bf16x2.
template<int SHIFT, bool RESID_BF, bool OUT_BF, bool GF8>
__global__ __launch_bounds__(256) void agg_ln(const int* __restrict__ row_ptr,
                                              const int2* __restrict__ epack,
                                              const float* __restrict__ dis,
                                              const void* __restrict__ hb,
                                              const int* __restrict__ nid,
                                              const void* __restrict__ resid,
                                              const float* __restrict__ bias,
                                              const float* __restrict__ gamma,
                                              const float* __restrict__ beta,
                                              void* __restrict__ out, int n) {
    int i = (blockIdx.x * 256 + threadIdx.x) >> 6;
    int lane = threadIdx.x & 63;
    if (i >= n) return;
    int iw = __builtin_amdgcn_readfirstlane(i);      // wave-uniform -> s_load
    int hri = nid ? nid[iw] : iw;
    float dl = dis[iw];
    float slo, shi;
    if (GF8) {
        uint ps = ((const ushort*)hb)[(size_t)hri * 64 + lane];
        f2v d = fp8x2_to_f2(ps);
        slo = d.x; shi = d.y;
    } else {
        uint ps = ((const uint*)hb)[(size_t)hri * 64 + lane];
        slo = bf_lo(ps); shi = bf_hi(ps);
    }
    float sx[4] = {dl * slo, 0.f, 0.f, 0.f};   // self-loop; *dl later -> dl^2
    float sy[4] = {dl * shi, 0.f, 0.f, 0.f};
    int e0 = row_ptr[iw], e1 = row_ptr[iw + 1];
    for (int j = e0; j < e1; j += 8) {
        i2v er[8];
        #pragma unroll
        for (int k = 0; k < 8; k++) {
            int idx = (j + k < e1) ? j + k : e0;     // clamp to a valid record
            er[k] = __builtin_nontemporal_load((const i2v*)(epack + idx));
        }
        uint qv[8];
        #pragma unroll
        for (int k = 0; k < 8; k++) {
            size_t row = ((uint)er[k].x >> SHIFT) & 0xffffu;
            qv[k] = GF8 ? (uint)((const ushort*)hb)[row * 64 + lane]
                        : ((const uint*)hb)[row * 64 + lane];
        }
        #pragma unroll
        for (int k = 0; k < 8; k++) {
            float w = (j + k < e1) ? __int_as_float(er[k].y) : 0.f;
            float lo, hi;
            if (GF8) { f2v d = fp8x2_to_f2(qv[k]); lo = d.x; hi = d.y; }
            else     { lo = bf_lo(qv[k]); hi = bf_hi(qv[k]); }
            sx[k & 3] += w * lo;
            sy[k & 3] += w * hi;
        }
    }
    float acc0 = (sx[0] + sx[1]) + (sx[2] + sx[3]);
    float acc1 = (sy[0] + sy[1]) + (sy[2] + sy[3]);
    float2 xr;
    if (RESID_BF) {
        uint pr = __builtin_nontemporal_load((const uint*)resid + (size_t)hri * 64 + lane);
        xr = make_float2(bf_lo(pr), bf_hi(pr));
    } else {
        xr = ((const float2*)resid)[(size_t)hri * 64 + lane];
    }
    float2 bi = ((const float2*)bias)[lane];
    float v0 = xr.x + dl * acc0 + bi.x;
    float v1 = xr.y + dl * acc1 + bi.y;
    float s1 = v0 + v1, s2 = v0 * v0 + v1 * v1;
    #pragma unroll
    for (int o = 32; o > 0; o >>= 1) {
        s1 += __shfl_xor(s1, o, 64);
        s2 += __shfl_xor(s2, o, 64);
    }
    float mu   = s1 * (1.0f / DIM);
    float var  = s2 * (1.0f / DIM) - mu * mu;
    float rstd = rsqrtf(var + LN_EPS);
    float2 ga = ((const float2*)gamma)[lane];
    float2 be = ((const float2*)beta)[lane];
    float o0 = (v0 - mu) * rstd * ga.x + be.x;
    float o1 = (v1 - mu) * rstd * ga.y + be.y;
    if (OUT_BF) {
        __builtin_nontemporal_store(f2bf(o0) | (f2bf(o1) << 16),
                                    (uint*)out + (size_t)i * 64 + lane);
    } else {
        f2v ov = {o0, o1};
        __builtin_nontemporal_store(ov, (f2v*)((float2*)out + (size_t)i * 64 + lane));
    }
}

// ---------------------------------------------------------------------------
extern "C" void kernel_launch(void* const* d_in, const int* in_sizes, int n_in,
                              void* d_out, int out_size, void* d_ws, size_t ws_size,
                              hipStream_t stream) {
    const int*   node_ids = (const int*)  d_in[0];
    const int*   ei       = (const int*)  d_in[1];   // [2, E]
    const float* ew       = (const float*)d_in[2];
    const float* emb      = (const float*)d_in[3];   // [VOCAB, 128]
    const float* W1       = (const float*)d_in[4];
    const float* b1       = (const float*)d_in[5];
    const float* W2       = (const float*)d_in[6];
    const float* b2       = (const float*)d_in[7];
    const float* g1       = (const float*)d_in[8];
    const float* be1      = (const float*)d_in[9];
    const float* g2       = (const float*)d_in[10];
    const float* be2      = (const float*)d_in[11];
    float* out = (float*)d_out;

    // workspace carve-out (256B aligned), total ~28 MB
    char* p = (char*)d_ws;
    auto alloc = [&](size_t bytes) {
        char* r = p;
        p += (bytes + 255) & ~(size_t)255;
        return r;
    };
    uchar*  h8      = (uchar*) alloc((size_t)N_NODES * DIM);     // 6.4 MB fp8
    uint*   x1b     = (uint*)  alloc((size_t)N_NODES * 64 * 4);  // 12.8 MB bf16x2
    uint*   hembB   = (uint*)  alloc((size_t)VOCAB * 64 * 4);    // 128 KB bf16x2
    ushort* Wp      = (ushort*)alloc((size_t)128 * 128 * 2);     // 32 KB B-frags
    ull*    pack    = (ull*)   alloc((size_t)N_NODES * 8);
    float*  disv    = (float*) alloc((size_t)N_NODES * 4);
    int*    row_ptr = (int*)   alloc((size_t)(N_NODES + 1) * 4);
    ushort* rank    = (ushort*)alloc((size_t)N_EDGES * 2);       // 1.2 MB
    int*    bsum    = (int*)   alloc(64 * 4);
    int2*   epack   = (int2*)  alloc((size_t)N_EDGES * 8);       // 4.8 MB

    int nb = (N_NODES + 1023) / 1024;            // 49
    int nbDeg = (N_EDGES / 8 + 255) / 256;       // 293
    int nmm = (VOCAB + 63) / 64;                 // 8

    // --- fused: CSR deg/rank + layer-1 matmul + W2 prepack (independent) ---
    (void)hipMemsetAsync(pack, 0, (size_t)N_NODES * 8, stream);
    deg_mm1_kernel<<<nbDeg + nmm + 64, 256, 0, stream>>>(
        ei, ew, pack, rank, N_EDGES, emb, W1, hembB, VOCAB, W2, Wp);
    scan_a<<<nb, 1024, 0, stream>>>(pack, disv, row_ptr, bsum, N_NODES);
    scan_c<<<nb, 1024, 0, stream>>>(row_ptr, bsum, N_NODES, N_EDGES, nb);
    scatter_kernel<<<(N_EDGES + 255) / 256, 256, 0, stream>>>(ei, ew, disv, node_ids,
                                                              row_ptr, rank, epack, N_EDGES);

    // --- Layer 1: bf16 gather table (LN1 amplifies errors -> keep bf16) ---
    agg_ln<16, false, true, false><<<(N_NODES + 3) / 4, 256, 0, stream>>>(
        row_ptr, epack, disv, hembB, node_ids, emb, b1, g1, be1, x1b, N_NODES);

    // --- Layer 2: MFMA matmul -> fp8 h2, fp8 gather agg+LN -> d_out ---
    mm2_mfma<<<(N_NODES / 16 + 3) / 4, 256, 0, stream>>>(x1b, Wp, h8, N_NODES);
    agg_ln<0, true, false, true><<<(N_NODES + 3) / 4, 256, 0, stream>>>(
        row_ptr, epack, disv, h8, nullptr, x1b, b2, g2, be2, out, N_NODES);
}